// Round 1
// baseline (7325.558 us; speedup 1.0000x reference)
//
#include <hip/hip_runtime.h>
#include <cstddef>
#include <cstdint>

#define NG   100
#define NPG  1000
#define NN   (NG * NPG)       // 100000 nodes
#define NE   (NN * 16)        // 1600000 edges
#define FIN  64
#define HID  128
#define RD   64
#define SLOPE 0.01f
#define EPSV  1e-5f
#define RSPLIT 8              // blocks per graph for the readout phi pass

__device__ __forceinline__ float leaky(float x) { return x >= 0.f ? x : SLOPE * x; }

// ---------------------------------------------------------------------------
// Degrees: out_deg over src, in_deg over dst (float counts).
// ---------------------------------------------------------------------------
__global__ __launch_bounds__(256) void degrees_k(const int* __restrict__ src,
                                                 const int* __restrict__ dst,
                                                 float* __restrict__ dout,
                                                 float* __restrict__ din) {
  int e = blockIdx.x * 256 + threadIdx.x;
  if (e < NE) {
    unsafeAtomicAdd(&dout[src[e]], 1.0f);
    unsafeAtomicAdd(&din[dst[e]], 1.0f);
  }
}

// ---------------------------------------------------------------------------
// Y[node][j] = rsqrt(max(deg_out,1)) * sum_k X[node][k] * W[k][j]
// W staged in LDS. 256 threads = 2 nodes x 128 out-feats, 64 nodes/block.
// ---------------------------------------------------------------------------
template <int K>
__global__ __launch_bounds__(256) void gemm_scaled_k(const float* __restrict__ X,
                                                     const float* __restrict__ W,
                                                     const float* __restrict__ degout,
                                                     float* __restrict__ Y) {
  __shared__ float Wl[K * HID];
  for (int i = threadIdx.x; i < K * HID; i += 256) Wl[i] = W[i];
  __syncthreads();
  const int j = threadIdx.x & (HID - 1);
  const int sub = threadIdx.x >> 7;  // 0..1
  const int base = blockIdx.x * 64;
  for (int it = 0; it < 32; ++it) {
    const int node = base + it * 2 + sub;
    if (node < NN) {
      const float* xr = X + (size_t)node * K;
      float a0 = 0.f, a1 = 0.f, a2 = 0.f, a3 = 0.f;
#pragma unroll
      for (int k = 0; k < K; k += 4) {
        a0 += xr[k + 0] * Wl[(k + 0) * HID + j];
        a1 += xr[k + 1] * Wl[(k + 1) * HID + j];
        a2 += xr[k + 2] * Wl[(k + 2) * HID + j];
        a3 += xr[k + 3] * Wl[(k + 3) * HID + j];
      }
      const float s = rsqrtf(fmaxf(degout[node], 1.0f));
      Y[(size_t)node * HID + j] = ((a0 + a1) + (a2 + a3)) * s;
    }
  }
}

// ---------------------------------------------------------------------------
// agg[dst] += ew * H0[src].  32 threads per edge, float4 per thread.
// ---------------------------------------------------------------------------
__global__ __launch_bounds__(256) void scatter_k(const float* __restrict__ H0,
                                                 const int* __restrict__ src,
                                                 const int* __restrict__ dst,
                                                 const float* __restrict__ ew,
                                                 float* __restrict__ AGG) {
  const long long idx = (long long)blockIdx.x * 256 + threadIdx.x;
  const long long e = idx >> 5;
  const int c = (int)(idx & 31);
  if (e >= NE) return;
  const int s = src[e];
  const int d = dst[e];
  const float w = ew[e];
  const float4 v = *(const float4*)(H0 + (size_t)s * HID + c * 4);
  float* p = AGG + (size_t)d * HID + c * 4;
  unsafeAtomicAdd(p + 0, v.x * w);
  unsafeAtomicAdd(p + 1, v.y * w);
  unsafeAtomicAdd(p + 2, v.z * w);
  unsafeAtomicAdd(p + 3, v.w * w);
}

// ---------------------------------------------------------------------------
// GraphNorm + leaky, in place on X (= agg; in_isqrt applied on the fly).
// One workgroup per graph; 256 threads = 2 node-lanes x 128 feats.
// ---------------------------------------------------------------------------
__global__ __launch_bounds__(256) void norm_k(float* __restrict__ X,
                                              const float* __restrict__ din,
                                              const float* __restrict__ alpha,
                                              const float* __restrict__ gamma,
                                              const float* __restrict__ beta) {
  __shared__ float red[256];
  __shared__ float meanS[HID], rstdS[HID], alphaS[HID], gammaS[HID], betaS[HID];
  const int tid = threadIdx.x;
  const int j = tid & (HID - 1);
  const int sub = tid >> 7;
  if (tid < HID) { alphaS[tid] = alpha[tid]; gammaS[tid] = gamma[tid]; betaS[tid] = beta[tid]; }
  const int base = blockIdx.x * NPG;

  // pass 1: mean
  float s = 0.f;
  for (int n = sub; n < NPG; n += 2) {
    const int node = base + n;
    const float isq = rsqrtf(fmaxf(din[node], 1.0f));
    s += X[(size_t)node * HID + j] * isq;
  }
  red[tid] = s;
  __syncthreads();
  if (tid < HID) meanS[tid] = (red[tid] + red[tid + HID]) * (1.0f / NPG);
  __syncthreads();
  const float am = alphaS[j] * meanS[j];

  // pass 2: var of (x - alpha*mean)
  float v = 0.f;
  for (int n = sub; n < NPG; n += 2) {
    const int node = base + n;
    const float isq = rsqrtf(fmaxf(din[node], 1.0f));
    const float d = X[(size_t)node * HID + j] * isq - am;
    v += d * d;
  }
  red[tid] = v;
  __syncthreads();
  if (tid < HID) rstdS[tid] = rsqrtf((red[tid] + red[tid + HID]) * (1.0f / NPG) + EPSV);
  __syncthreads();
  const float rs = rstdS[j];
  const float gm = gammaS[j];
  const float bt = betaS[j];

  // pass 3: normalize + leaky, in place
  for (int n = sub; n < NPG; n += 2) {
    const int node = base + n;
    const float isq = rsqrtf(fmaxf(din[node], 1.0f));
    const float d = X[(size_t)node * HID + j] * isq - am;
    X[(size_t)node * HID + j] = leaky(gm * d * rs + bt);
  }
}

// ---------------------------------------------------------------------------
// Readout part 1: per (graph, 1/RSPLIT of nodes) block computes partial
// sums of phi = leaky(h @ w1 + b1) and of h itself; atomicAdd into [NG,128].
// ---------------------------------------------------------------------------
__global__ __launch_bounds__(256) void phi_pool_k(const float* __restrict__ Hn,
                                                  const float* __restrict__ w1,
                                                  const float* __restrict__ b1,
                                                  float* __restrict__ phi_sum,
                                                  float* __restrict__ h_sum) {
  __shared__ float Wl[HID * HID];
  __shared__ float hrow[2][HID];
  const int g = blockIdx.x / RSPLIT;
  const int part = blockIdx.x % RSPLIT;
  for (int i = threadIdx.x; i < HID * HID; i += 256) Wl[i] = w1[i];
  const int j = threadIdx.x & (HID - 1);
  const int sub = threadIdx.x >> 7;
  const float bj = b1[j];
  __syncthreads();

  float ps = 0.f, hs = 0.f;
  const int chunk = NPG / RSPLIT;  // 125
  const int base = g * NPG + part * chunk;
  for (int n = 0; n < chunk; n += 2) {
    const bool valid = (n + sub) < chunk;
    if (valid) hrow[sub][j] = Hn[(size_t)(base + n + sub) * HID + j];
    __syncthreads();
    if (valid) {
      float a0 = 0.f, a1 = 0.f, a2 = 0.f, a3 = 0.f;
#pragma unroll
      for (int k = 0; k < HID; k += 4) {
        a0 += hrow[sub][k + 0] * Wl[(k + 0) * HID + j];
        a1 += hrow[sub][k + 1] * Wl[(k + 1) * HID + j];
        a2 += hrow[sub][k + 2] * Wl[(k + 2) * HID + j];
        a3 += hrow[sub][k + 3] * Wl[(k + 3) * HID + j];
      }
      ps += leaky(bj + ((a0 + a1) + (a2 + a3)));
      hs += hrow[sub][j];
    }
    __syncthreads();
  }
  unsafeAtomicAdd(&phi_sum[g * HID + j], ps);
  unsafeAtomicAdd(&h_sum[g * HID + j], hs);
}

// ---------------------------------------------------------------------------
// Readout part 2: r = leaky(mean_phi @ w2 + b2); out gets leaky(r) at roff,
// leaky(mean_h) at moff. One 64-thread block per graph.
// ---------------------------------------------------------------------------
__global__ __launch_bounds__(64) void finalize_k(const float* __restrict__ phi_sum,
                                                 const float* __restrict__ h_sum,
                                                 const float* __restrict__ w2,
                                                 const float* __restrict__ b2,
                                                 float* __restrict__ out,
                                                 int roff, int moff) {
  const int g = blockIdx.x;
  const int j = threadIdx.x;  // 0..63
  float acc = b2[j];
#pragma unroll 8
  for (int k = 0; k < HID; ++k)
    acc += (phi_sum[g * HID + k] * (1.0f / NPG)) * w2[k * RD + j];
  const float r = leaky(acc);
  out[g * 384 + roff + j] = leaky(r);
  out[g * 384 + moff + j] = leaky(h_sum[g * HID + j] * (1.0f / NPG));
  out[g * 384 + moff + 64 + j] = leaky(h_sum[g * HID + 64 + j] * (1.0f / NPG));
}

// ---------------------------------------------------------------------------
extern "C" void kernel_launch(void* const* d_in, const int* in_sizes, int n_in,
                              void* d_out, int out_size, void* d_ws, size_t ws_size,
                              hipStream_t stream) {
  const float* node_feats = (const float*)d_in[0];
  const float* ew   = (const float*)d_in[1];
  const float* W1   = (const float*)d_in[2];
  const float* W2   = (const float*)d_in[3];
  const float* g1a  = (const float*)d_in[4];
  const float* g1g  = (const float*)d_in[5];
  const float* g1b  = (const float*)d_in[6];
  const float* g2a  = (const float*)d_in[7];
  const float* g2g  = (const float*)d_in[8];
  const float* g2b  = (const float*)d_in[9];
  const float* r1w1 = (const float*)d_in[10];
  const float* r1b1 = (const float*)d_in[11];
  const float* r1w2 = (const float*)d_in[12];
  const float* r1b2 = (const float*)d_in[13];
  const float* r2w1 = (const float*)d_in[14];
  const float* r2b1 = (const float*)d_in[15];
  const float* r2w2 = (const float*)d_in[16];
  const float* r2b2 = (const float*)d_in[17];
  const int* src = (const int*)d_in[18];
  const int* dst = (const int*)d_in[19];
  float* out = (float*)d_out;

  float* ws      = (float*)d_ws;
  float* deg_out = ws;                        // NN
  float* deg_in  = deg_out + NN;              // NN
  float* ps1     = deg_in + NN;               // NG*HID
  float* hs1     = ps1 + NG * HID;
  float* ps2     = hs1 + NG * HID;
  float* hs2     = ps2 + NG * HID;
  float* bufA    = hs2 + NG * HID;            // NN*HID
  float* bufB    = bufA + (size_t)NN * HID;   // NN*HID

  // zero: degrees + pooled sums (ws is poisoned 0xAA each call)
  hipMemsetAsync(ws, 0, (size_t)(2 * NN + 4 * NG * HID) * sizeof(float), stream);
  degrees_k<<<(NE + 255) / 256, 256, 0, stream>>>(src, dst, deg_out, deg_in);

  // ---- layer 1 ----
  gemm_scaled_k<FIN><<<(NN + 63) / 64, 256, 0, stream>>>(node_feats, W1, deg_out, bufA);
  hipMemsetAsync(bufB, 0, (size_t)NN * HID * sizeof(float), stream);
  scatter_k<<<(int)((long long)NE * 32 / 256), 256, 0, stream>>>(bufA, src, dst, ew, bufB);
  norm_k<<<NG, 256, 0, stream>>>(bufB, deg_in, g1a, g1g, g1b);
  phi_pool_k<<<NG * RSPLIT, 256, 0, stream>>>(bufB, r1w1, r1b1, ps1, hs1);
  finalize_k<<<NG, 64, 0, stream>>>(ps1, hs1, r1w2, r1b2, out, 0, 64);

  // ---- layer 2 ----
  gemm_scaled_k<HID><<<(NN + 63) / 64, 256, 0, stream>>>(bufB, W2, deg_out, bufA);
  hipMemsetAsync(bufB, 0, (size_t)NN * HID * sizeof(float), stream);
  scatter_k<<<(int)((long long)NE * 32 / 256), 256, 0, stream>>>(bufA, src, dst, ew, bufB);
  norm_k<<<NG, 256, 0, stream>>>(bufB, deg_in, g2a, g2g, g2b);
  phi_pool_k<<<NG * RSPLIT, 256, 0, stream>>>(bufB, r2w1, r2b1, ps2, hs2);
  finalize_k<<<NG, 64, 0, stream>>>(ps2, hs2, r2w2, r2b2, out, 192, 256);
}

// Round 2
// 2160.697 us; speedup vs baseline: 3.3904x; 3.3904x over previous
//
#include <hip/hip_runtime.h>
#include <cstddef>
#include <cstdint>

#define NG   100
#define NPG  1000
#define NN   (NG * NPG)       // 100000 nodes
#define NE   (NN * 16)        // 1600000 edges
#define EPG  (NE / NG)        // 16000 edges per graph (edges are graph-local)
#define FIN  64
#define HID  128
#define RD   64
#define SLOPE 0.01f
#define EPSV  1e-5f
#define RSPLIT 8              // blocks per graph for the readout phi pass

__device__ __forceinline__ float leaky(float x) { return x >= 0.f ? x : SLOPE * x; }

// ---------------------------------------------------------------------------
// Degree counts (int): out over src, in over dst.
// ---------------------------------------------------------------------------
__global__ __launch_bounds__(256) void degrees_k(const int* __restrict__ src,
                                                 const int* __restrict__ dst,
                                                 int* __restrict__ cout_,
                                                 int* __restrict__ cin_) {
  int e = blockIdx.x * 256 + threadIdx.x;
  if (e < NE) {
    atomicAdd(&cout_[src[e]], 1);
    atomicAdd(&cin_[dst[e]], 1);
  }
}

// ---------------------------------------------------------------------------
// Per-graph exclusive scan of in-degree counts -> CSR offsets + cursor copy.
// One 256-thread block per graph scans its 1000 counts (4 elems/thread).
// Graph g's CSR segment is exactly [g*EPG, (g+1)*EPG) since edges are local.
// ---------------------------------------------------------------------------
__global__ __launch_bounds__(256) void scan_k(const int* __restrict__ cin_,
                                              int* __restrict__ offs,
                                              int* __restrict__ cursor) {
  __shared__ int tsum[256];
  const int g = blockIdx.x;
  const int t = threadIdx.x;
  const int base = g * NPG;
  int v[4];
  int loc = 0;
#pragma unroll
  for (int k = 0; k < 4; ++k) {
    const int idx = t * 4 + k;
    v[k] = (idx < NPG) ? cin_[base + idx] : 0;
    loc += v[k];
  }
  tsum[t] = loc;
  __syncthreads();
  // Hillis-Steele inclusive scan over 256 thread sums
  for (int d = 1; d < 256; d <<= 1) {
    int x = (t >= d) ? tsum[t - d] : 0;
    __syncthreads();
    tsum[t] += x;
    __syncthreads();
  }
  int run = (t > 0 ? tsum[t - 1] : 0) + g * EPG;  // exclusive prefix, graph base
#pragma unroll
  for (int k = 0; k < 4; ++k) {
    const int idx = t * 4 + k;
    if (idx < NPG) {
      offs[base + idx] = run;
      cursor[base + idx] = run;
      run += v[k];
    }
  }
}

// ---------------------------------------------------------------------------
// CSR build: slot each edge's (src, w) under its dst bucket.
// ---------------------------------------------------------------------------
__global__ __launch_bounds__(256) void csr_build_k(const int* __restrict__ src,
                                                   const int* __restrict__ dst,
                                                   const float* __restrict__ ew,
                                                   int* __restrict__ cursor,
                                                   int* __restrict__ csr_src,
                                                   float* __restrict__ csr_w) {
  int e = blockIdx.x * 256 + threadIdx.x;
  if (e < NE) {
    const int pos = atomicAdd(&cursor[dst[e]], 1);
    csr_src[pos] = src[e];
    csr_w[pos] = ew[e];
  }
}

// ---------------------------------------------------------------------------
// Y[node][j] = rsqrt(max(out_deg,1)) * sum_k X[node][k] * W[k][j]
// W staged in LDS. 256 threads = 2 nodes x 128 out-feats, 64 nodes/block.
// ---------------------------------------------------------------------------
template <int K>
__global__ __launch_bounds__(256) void gemm_scaled_k(const float* __restrict__ X,
                                                     const float* __restrict__ W,
                                                     const int* __restrict__ cout_,
                                                     float* __restrict__ Y) {
  __shared__ float Wl[K * HID];
  for (int i = threadIdx.x; i < K * HID; i += 256) Wl[i] = W[i];
  __syncthreads();
  const int j = threadIdx.x & (HID - 1);
  const int sub = threadIdx.x >> 7;  // 0..1
  const int base = blockIdx.x * 64;
  for (int it = 0; it < 32; ++it) {
    const int node = base + it * 2 + sub;
    if (node < NN) {
      const float* xr = X + (size_t)node * K;
      float a0 = 0.f, a1 = 0.f, a2 = 0.f, a3 = 0.f;
#pragma unroll
      for (int k = 0; k < K; k += 4) {
        a0 += xr[k + 0] * Wl[(k + 0) * HID + j];
        a1 += xr[k + 1] * Wl[(k + 1) * HID + j];
        a2 += xr[k + 2] * Wl[(k + 2) * HID + j];
        a3 += xr[k + 3] * Wl[(k + 3) * HID + j];
      }
      const float s = rsqrtf(fmaxf((float)cout_[node], 1.0f));
      Y[(size_t)node * HID + j] = ((a0 + a1) + (a2 + a3)) * s;
    }
  }
}

// ---------------------------------------------------------------------------
// Atomic-free aggregation: AGG[n] = sum_{e in CSR[n]} w_e * H[src_e].
// One 64-lane wave per node (float2 per lane); 256-thread block = 4 nodes.
// ---------------------------------------------------------------------------
__global__ __launch_bounds__(256) void gather_k(const float* __restrict__ H,
                                                const int* __restrict__ csr_src,
                                                const float* __restrict__ csr_w,
                                                const int* __restrict__ offs,
                                                const int* __restrict__ cin_,
                                                float* __restrict__ AGG) {
  const int node = blockIdx.x * 4 + (threadIdx.x >> 6);
  const int lane = threadIdx.x & 63;
  if (node >= NN) return;
  const int off = offs[node];
  const int cnt = cin_[node];
  float ax = 0.f, ay = 0.f, bx = 0.f, by = 0.f;
  int i = 0;
  for (; i + 2 <= cnt; i += 2) {
    const int s0 = csr_src[off + i];
    const int s1 = csr_src[off + i + 1];
    const float w0 = csr_w[off + i];
    const float w1 = csr_w[off + i + 1];
    const float2 v0 = *(const float2*)(H + (size_t)s0 * HID + lane * 2);
    const float2 v1 = *(const float2*)(H + (size_t)s1 * HID + lane * 2);
    ax += w0 * v0.x; ay += w0 * v0.y;
    bx += w1 * v1.x; by += w1 * v1.y;
  }
  if (i < cnt) {
    const int s0 = csr_src[off + i];
    const float w0 = csr_w[off + i];
    const float2 v0 = *(const float2*)(H + (size_t)s0 * HID + lane * 2);
    ax += w0 * v0.x; ay += w0 * v0.y;
  }
  float2 r;
  r.x = ax + bx;
  r.y = ay + by;
  *(float2*)(AGG + (size_t)node * HID + lane * 2) = r;
}

// ---------------------------------------------------------------------------
// GraphNorm + leaky, in place on X (= agg; in_isqrt applied on the fly).
// One workgroup per graph; 256 threads = 2 node-lanes x 128 feats.
// ---------------------------------------------------------------------------
__global__ __launch_bounds__(256) void norm_k(float* __restrict__ X,
                                              const int* __restrict__ cin_,
                                              const float* __restrict__ alpha,
                                              const float* __restrict__ gamma,
                                              const float* __restrict__ beta) {
  __shared__ float red[256];
  __shared__ float meanS[HID], rstdS[HID], alphaS[HID], gammaS[HID], betaS[HID];
  const int tid = threadIdx.x;
  const int j = tid & (HID - 1);
  const int sub = tid >> 7;
  if (tid < HID) { alphaS[tid] = alpha[tid]; gammaS[tid] = gamma[tid]; betaS[tid] = beta[tid]; }
  const int base = blockIdx.x * NPG;

  // pass 1: mean
  float s = 0.f;
  for (int n = sub; n < NPG; n += 2) {
    const int node = base + n;
    const float isq = rsqrtf(fmaxf((float)cin_[node], 1.0f));
    s += X[(size_t)node * HID + j] * isq;
  }
  red[tid] = s;
  __syncthreads();
  if (tid < HID) meanS[tid] = (red[tid] + red[tid + HID]) * (1.0f / NPG);
  __syncthreads();
  const float am = alphaS[j] * meanS[j];

  // pass 2: var of (x - alpha*mean)
  float v = 0.f;
  for (int n = sub; n < NPG; n += 2) {
    const int node = base + n;
    const float isq = rsqrtf(fmaxf((float)cin_[node], 1.0f));
    const float d = X[(size_t)node * HID + j] * isq - am;
    v += d * d;
  }
  red[tid] = v;
  __syncthreads();
  if (tid < HID) rstdS[tid] = rsqrtf((red[tid] + red[tid + HID]) * (1.0f / NPG) + EPSV);
  __syncthreads();
  const float rs = rstdS[j];
  const float gm = gammaS[j];
  const float bt = betaS[j];

  // pass 3: normalize + leaky, in place
  for (int n = sub; n < NPG; n += 2) {
    const int node = base + n;
    const float isq = rsqrtf(fmaxf((float)cin_[node], 1.0f));
    const float d = X[(size_t)node * HID + j] * isq - am;
    X[(size_t)node * HID + j] = leaky(gm * d * rs + bt);
  }
}

// ---------------------------------------------------------------------------
// Readout part 1: per (graph, 1/RSPLIT of nodes) block computes partial
// sums of phi = leaky(h @ w1 + b1) and of h itself; atomicAdd into [NG,128].
// ---------------------------------------------------------------------------
__global__ __launch_bounds__(256) void phi_pool_k(const float* __restrict__ Hn,
                                                  const float* __restrict__ w1,
                                                  const float* __restrict__ b1,
                                                  float* __restrict__ phi_sum,
                                                  float* __restrict__ h_sum) {
  __shared__ float Wl[HID * HID];
  __shared__ float hrow[2][HID];
  const int g = blockIdx.x / RSPLIT;
  const int part = blockIdx.x % RSPLIT;
  for (int i = threadIdx.x; i < HID * HID; i += 256) Wl[i] = w1[i];
  const int j = threadIdx.x & (HID - 1);
  const int sub = threadIdx.x >> 7;
  const float bj = b1[j];
  __syncthreads();

  float ps = 0.f, hs = 0.f;
  const int chunk = NPG / RSPLIT;  // 125
  const int base = g * NPG + part * chunk;
  for (int n = 0; n < chunk; n += 2) {
    const bool valid = (n + sub) < chunk;
    if (valid) hrow[sub][j] = Hn[(size_t)(base + n + sub) * HID + j];
    __syncthreads();
    if (valid) {
      float a0 = 0.f, a1 = 0.f, a2 = 0.f, a3 = 0.f;
#pragma unroll
      for (int k = 0; k < HID; k += 4) {
        a0 += hrow[sub][k + 0] * Wl[(k + 0) * HID + j];
        a1 += hrow[sub][k + 1] * Wl[(k + 1) * HID + j];
        a2 += hrow[sub][k + 2] * Wl[(k + 2) * HID + j];
        a3 += hrow[sub][k + 3] * Wl[(k + 3) * HID + j];
      }
      ps += leaky(bj + ((a0 + a1) + (a2 + a3)));
      hs += hrow[sub][j];
    }
    __syncthreads();
  }
  unsafeAtomicAdd(&phi_sum[g * HID + j], ps);
  unsafeAtomicAdd(&h_sum[g * HID + j], hs);
}

// ---------------------------------------------------------------------------
// Readout part 2: r = leaky(mean_phi @ w2 + b2); out gets leaky(r) at roff,
// leaky(mean_h) at moff. One 64-thread block per graph.
// ---------------------------------------------------------------------------
__global__ __launch_bounds__(64) void finalize_k(const float* __restrict__ phi_sum,
                                                 const float* __restrict__ h_sum,
                                                 const float* __restrict__ w2,
                                                 const float* __restrict__ b2,
                                                 float* __restrict__ out,
                                                 int roff, int moff) {
  const int g = blockIdx.x;
  const int j = threadIdx.x;  // 0..63
  float acc = b2[j];
#pragma unroll 8
  for (int k = 0; k < HID; ++k)
    acc += (phi_sum[g * HID + k] * (1.0f / NPG)) * w2[k * RD + j];
  const float r = leaky(acc);
  out[g * 384 + roff + j] = leaky(r);
  out[g * 384 + moff + j] = leaky(h_sum[g * HID + j] * (1.0f / NPG));
  out[g * 384 + moff + 64 + j] = leaky(h_sum[g * HID + 64 + j] * (1.0f / NPG));
}

// ---------------------------------------------------------------------------
extern "C" void kernel_launch(void* const* d_in, const int* in_sizes, int n_in,
                              void* d_out, int out_size, void* d_ws, size_t ws_size,
                              hipStream_t stream) {
  const float* node_feats = (const float*)d_in[0];
  const float* ew   = (const float*)d_in[1];
  const float* W1   = (const float*)d_in[2];
  const float* W2   = (const float*)d_in[3];
  const float* g1a  = (const float*)d_in[4];
  const float* g1g  = (const float*)d_in[5];
  const float* g1b  = (const float*)d_in[6];
  const float* g2a  = (const float*)d_in[7];
  const float* g2g  = (const float*)d_in[8];
  const float* g2b  = (const float*)d_in[9];
  const float* r1w1 = (const float*)d_in[10];
  const float* r1b1 = (const float*)d_in[11];
  const float* r1w2 = (const float*)d_in[12];
  const float* r1b2 = (const float*)d_in[13];
  const float* r2w1 = (const float*)d_in[14];
  const float* r2b1 = (const float*)d_in[15];
  const float* r2w2 = (const float*)d_in[16];
  const float* r2b2 = (const float*)d_in[17];
  const int* src = (const int*)d_in[18];
  const int* dst = (const int*)d_in[19];
  float* out = (float*)d_out;

  // workspace layout (zeroed region first)
  char* wsb = (char*)d_ws;
  int*   cin     = (int*)wsb;                         // NN    } zeroed
  int*   cout_   = cin + NN;                          // NN    }
  float* ps1     = (float*)(cout_ + NN);              // NG*HID}
  float* hs1     = ps1 + NG * HID;                    //       }
  float* ps2     = hs1 + NG * HID;                    //       }
  float* hs2     = ps2 + NG * HID;                    //       }
  int*   offs    = (int*)(hs2 + NG * HID);            // NN
  int*   cursor  = offs + NN;                         // NN
  int*   csr_src = cursor + NN;                       // NE
  float* csr_w   = (float*)(csr_src + NE);            // NE
  float* bufA    = csr_w + NE;                        // NN*HID
  float* bufB    = bufA + (size_t)NN * HID;           // NN*HID

  const size_t zero_bytes = (size_t)(2 * NN) * sizeof(int) + (size_t)(4 * NG * HID) * sizeof(float);
  hipMemsetAsync(d_ws, 0, zero_bytes, stream);

  // graph structure (per call; ws is re-poisoned each launch)
  degrees_k<<<(NE + 255) / 256, 256, 0, stream>>>(src, dst, cout_, cin);
  scan_k<<<NG, 256, 0, stream>>>(cin, offs, cursor);
  csr_build_k<<<(NE + 255) / 256, 256, 0, stream>>>(src, dst, ew, cursor, csr_src, csr_w);

  // ---- layer 1 ----
  gemm_scaled_k<FIN><<<(NN + 63) / 64, 256, 0, stream>>>(node_feats, W1, cout_, bufA);
  gather_k<<<NN / 4, 256, 0, stream>>>(bufA, csr_src, csr_w, offs, cin, bufB);
  norm_k<<<NG, 256, 0, stream>>>(bufB, cin, g1a, g1g, g1b);
  phi_pool_k<<<NG * RSPLIT, 256, 0, stream>>>(bufB, r1w1, r1b1, ps1, hs1);
  finalize_k<<<NG, 64, 0, stream>>>(ps1, hs1, r1w2, r1b2, out, 0, 64);

  // ---- layer 2 ----
  gemm_scaled_k<HID><<<(NN + 63) / 64, 256, 0, stream>>>(bufB, W2, cout_, bufA);
  gather_k<<<NN / 4, 256, 0, stream>>>(bufA, csr_src, csr_w, offs, cin, bufB);
  norm_k<<<NG, 256, 0, stream>>>(bufB, cin, g2a, g2g, g2b);
  phi_pool_k<<<NG * RSPLIT, 256, 0, stream>>>(bufB, r2w1, r2b1, ps2, hs2);
  finalize_k<<<NG, 64, 0, stream>>>(ps2, hs2, r2w2, r2b2, out, 192, 256);
}

// Round 3
// 1494.430 us; speedup vs baseline: 4.9019x; 1.4458x over previous
//
#include <hip/hip_runtime.h>
#include <cstddef>
#include <cstdint>

#define NG   100
#define NPG  1000
#define NN   (NG * NPG)       // 100000 nodes
#define NE   (NN * 16)        // 1600000 edges
#define EPG  (NE / NG)        // 16000 edges per graph (edges are graph-local)
#define FIN  64
#define HID  128
#define RD   64
#define SLOPE 0.01f
#define EPSV  1e-5f
#define RSPLIT 8              // blocks per graph for the readout phi pass
#define GSN   40              // nodes per gather block (40 | 1000 -> graph-aligned)

__device__ __forceinline__ float leaky(float x) { return x >= 0.f ? x : SLOPE * x; }

// ---------------------------------------------------------------------------
// Degree counts (int): out over src, in over dst.
// ---------------------------------------------------------------------------
__global__ __launch_bounds__(256) void degrees_k(const int* __restrict__ src,
                                                 const int* __restrict__ dst,
                                                 int* __restrict__ cout_,
                                                 int* __restrict__ cin_) {
  int e = blockIdx.x * 256 + threadIdx.x;
  if (e < NE) {
    atomicAdd(&cout_[src[e]], 1);
    atomicAdd(&cin_[dst[e]], 1);
  }
}

// ---------------------------------------------------------------------------
// Per-graph exclusive scan of in-degree counts -> CSR offsets + cursor copy.
// ---------------------------------------------------------------------------
__global__ __launch_bounds__(256) void scan_k(const int* __restrict__ cin_,
                                              int* __restrict__ offs,
                                              int* __restrict__ cursor) {
  __shared__ int tsum[256];
  const int g = blockIdx.x;
  const int t = threadIdx.x;
  const int base = g * NPG;
  int v[4];
  int loc = 0;
#pragma unroll
  for (int k = 0; k < 4; ++k) {
    const int idx = t * 4 + k;
    v[k] = (idx < NPG) ? cin_[base + idx] : 0;
    loc += v[k];
  }
  tsum[t] = loc;
  __syncthreads();
  for (int d = 1; d < 256; d <<= 1) {
    int x = (t >= d) ? tsum[t - d] : 0;
    __syncthreads();
    tsum[t] += x;
    __syncthreads();
  }
  int run = (t > 0 ? tsum[t - 1] : 0) + g * EPG;
#pragma unroll
  for (int k = 0; k < 4; ++k) {
    const int idx = t * 4 + k;
    if (idx < NPG) {
      offs[base + idx] = run;
      cursor[base + idx] = run;
      run += v[k];
    }
  }
}

// ---------------------------------------------------------------------------
// CSR build: slot each edge's (src, w) under its dst bucket.
// ---------------------------------------------------------------------------
__global__ __launch_bounds__(256) void csr_build_k(const int* __restrict__ src,
                                                   const int* __restrict__ dst,
                                                   const float* __restrict__ ew,
                                                   int* __restrict__ cursor,
                                                   int* __restrict__ csr_src,
                                                   float* __restrict__ csr_w) {
  int e = blockIdx.x * 256 + threadIdx.x;
  if (e < NE) {
    const int pos = atomicAdd(&cursor[dst[e]], 1);
    csr_src[pos] = src[e];
    csr_w[pos] = ew[e];
  }
}

// ---------------------------------------------------------------------------
// Layer-1 GEMM: Y[node][j] = rsqrt(max(out_deg,1)) * sum_k X[node][k]*W[k][j]
// ---------------------------------------------------------------------------
__global__ __launch_bounds__(256) void gemm1_k(const float* __restrict__ X,
                                               const float* __restrict__ W,
                                               const int* __restrict__ cout_,
                                               float* __restrict__ Y) {
  __shared__ float Wl[FIN * HID];
  for (int i = threadIdx.x; i < FIN * HID; i += 256) Wl[i] = W[i];
  __syncthreads();
  const int j = threadIdx.x & (HID - 1);
  const int sub = threadIdx.x >> 7;
  const int base = blockIdx.x * 64;
  for (int it = 0; it < 32; ++it) {
    const int node = base + it * 2 + sub;
    if (node < NN) {
      const float* xr = X + (size_t)node * FIN;
      float a0 = 0.f, a1 = 0.f, a2 = 0.f, a3 = 0.f;
#pragma unroll
      for (int k = 0; k < FIN; k += 4) {
        a0 += xr[k + 0] * Wl[(k + 0) * HID + j];
        a1 += xr[k + 1] * Wl[(k + 1) * HID + j];
        a2 += xr[k + 2] * Wl[(k + 2) * HID + j];
        a3 += xr[k + 3] * Wl[(k + 3) * HID + j];
      }
      const float s = rsqrtf(fmaxf((float)cout_[node], 1.0f));
      Y[(size_t)node * HID + j] = ((a0 + a1) + (a2 + a3)) * s;
    }
  }
}

// ---------------------------------------------------------------------------
// Layer-2 GEMM with fused GraphNorm apply on the input:
//   xn[k] = leaky(A[g][k]*X[node][k] + B[g][k])   (staged in LDS)
//   Y[node][j] = out_isqrt * sum_k xn[k] * W[k][j]
// ---------------------------------------------------------------------------
__global__ __launch_bounds__(256) void gemm_norm_k(const float* __restrict__ X,
                                                   const float* __restrict__ W,
                                                   const float* __restrict__ An,
                                                   const float* __restrict__ Bn,
                                                   const int* __restrict__ cout_,
                                                   float* __restrict__ Y) {
  __shared__ float Wl[HID * HID];
  __shared__ float hrow[2][HID];
  for (int i = threadIdx.x; i < HID * HID; i += 256) Wl[i] = W[i];
  const int j = threadIdx.x & (HID - 1);
  const int sub = threadIdx.x >> 7;
  const int base = blockIdx.x * 64;
  __syncthreads();
  for (int it = 0; it < 32; ++it) {
    const int node = base + it * 2 + sub;
    const bool valid = node < NN;
    if (valid) {
      const int g = node / NPG;
      const float x = X[(size_t)node * HID + j];
      hrow[sub][j] = leaky(fmaf(An[g * HID + j], x, Bn[g * HID + j]));
    }
    __syncthreads();
    if (valid) {
      float a0 = 0.f, a1 = 0.f, a2 = 0.f, a3 = 0.f;
#pragma unroll
      for (int k = 0; k < HID; k += 4) {
        a0 += hrow[sub][k + 0] * Wl[(k + 0) * HID + j];
        a1 += hrow[sub][k + 1] * Wl[(k + 1) * HID + j];
        a2 += hrow[sub][k + 2] * Wl[(k + 2) * HID + j];
        a3 += hrow[sub][k + 3] * Wl[(k + 3) * HID + j];
      }
      const float s = rsqrtf(fmaxf((float)cout_[node], 1.0f));
      Y[(size_t)node * HID + j] = ((a0 + a1) + (a2 + a3)) * s;
    }
    __syncthreads();
  }
}

// ---------------------------------------------------------------------------
// Atomic-free aggregation + in_isqrt scale + fused per-graph stats:
//   x[n] = in_isqrt[n] * sum_{e in CSR[n]} w_e * H[src_e]   -> AGG
//   partial Sum(x), Sum(x^2) per (graph, feat) -> atomics into sx, sq.
// Block = 4 waves; wave w handles nodes {base+w, base+w+4, ...} of a 40-node
// graph-aligned strip; 2 feats per lane.
// ---------------------------------------------------------------------------
__global__ __launch_bounds__(256) void gather_k(const float* __restrict__ H,
                                                const int* __restrict__ csr_src,
                                                const float* __restrict__ csr_w,
                                                const int* __restrict__ offs,
                                                const int* __restrict__ cin_,
                                                float* __restrict__ AGG,
                                                float* __restrict__ sx,
                                                float* __restrict__ sq) {
  __shared__ float redx[4][HID];
  __shared__ float redq[4][HID];
  const int wave = threadIdx.x >> 6;
  const int lane = threadIdx.x & 63;
  const int base = blockIdx.x * GSN;
  const int g = base / NPG;  // exact: GSN | NPG

  float sxa = 0.f, sxb = 0.f, sqa = 0.f, sqb = 0.f;
  for (int n = base + wave; n < base + GSN; n += 4) {
    const int off = offs[n];
    const int cnt = cin_[n];
    const float isq = rsqrtf(fmaxf((float)cnt, 1.0f));
    float ax = 0.f, ay = 0.f, bx = 0.f, by = 0.f;
    int i = 0;
    for (; i + 2 <= cnt; i += 2) {
      const int s0 = csr_src[off + i];
      const int s1 = csr_src[off + i + 1];
      const float w0 = csr_w[off + i];
      const float w1 = csr_w[off + i + 1];
      const float2 v0 = *(const float2*)(H + (size_t)s0 * HID + lane * 2);
      const float2 v1 = *(const float2*)(H + (size_t)s1 * HID + lane * 2);
      ax += w0 * v0.x; ay += w0 * v0.y;
      bx += w1 * v1.x; by += w1 * v1.y;
    }
    if (i < cnt) {
      const int s0 = csr_src[off + i];
      const float w0 = csr_w[off + i];
      const float2 v0 = *(const float2*)(H + (size_t)s0 * HID + lane * 2);
      ax += w0 * v0.x; ay += w0 * v0.y;
    }
    float2 r;
    r.x = (ax + bx) * isq;
    r.y = (ay + by) * isq;
    *(float2*)(AGG + (size_t)n * HID + lane * 2) = r;
    sxa += r.x; sxb += r.y;
    sqa += r.x * r.x; sqb += r.y * r.y;
  }
  redx[wave][lane * 2] = sxa; redx[wave][lane * 2 + 1] = sxb;
  redq[wave][lane * 2] = sqa; redq[wave][lane * 2 + 1] = sqb;
  __syncthreads();
  const int tid = threadIdx.x;
  if (tid < HID) {
    unsafeAtomicAdd(&sx[g * HID + tid],
                    redx[0][tid] + redx[1][tid] + redx[2][tid] + redx[3][tid]);
  } else {
    const int t = tid - HID;
    unsafeAtomicAdd(&sq[g * HID + t],
                    redq[0][t] + redq[1][t] + redq[2][t] + redq[3][t]);
  }
}

// ---------------------------------------------------------------------------
// Fold stats into affine: normalized = A*x + B per (graph, feat).
// ---------------------------------------------------------------------------
__global__ __launch_bounds__(HID) void stats_k(const float* __restrict__ sx,
                                               const float* __restrict__ sq,
                                               const float* __restrict__ alpha,
                                               const float* __restrict__ gamma,
                                               const float* __restrict__ beta,
                                               float* __restrict__ An,
                                               float* __restrict__ Bn) {
  const int g = blockIdx.x;
  const int j = threadIdx.x;
  const float mean = sx[g * HID + j] * (1.0f / NPG);
  const float ex2 = sq[g * HID + j] * (1.0f / NPG);
  const float am = alpha[j] * mean;
  float var = ex2 - 2.0f * am * mean + am * am;
  var = fmaxf(var, 0.0f);
  const float rstd = rsqrtf(var + EPSV);
  const float A = gamma[j] * rstd;
  An[g * HID + j] = A;
  Bn[g * HID + j] = beta[j] - A * am;
}

// ---------------------------------------------------------------------------
// Readout part 1 with fused norm apply: per (graph, part) block pools
// phi = leaky(xn @ w1 + b1) and xn itself, xn = leaky(A*x+B).
// ---------------------------------------------------------------------------
__global__ __launch_bounds__(256) void phi_pool_k(const float* __restrict__ Xr,
                                                  const float* __restrict__ An,
                                                  const float* __restrict__ Bn,
                                                  const float* __restrict__ w1,
                                                  const float* __restrict__ b1,
                                                  float* __restrict__ phi_sum,
                                                  float* __restrict__ h_sum) {
  __shared__ float Wl[HID * HID];
  __shared__ float hrow[2][HID];
  const int g = blockIdx.x / RSPLIT;
  const int part = blockIdx.x % RSPLIT;
  for (int i = threadIdx.x; i < HID * HID; i += 256) Wl[i] = w1[i];
  const int j = threadIdx.x & (HID - 1);
  const int sub = threadIdx.x >> 7;
  const float bj = b1[j];
  const float aj = An[g * HID + j];
  const float cj = Bn[g * HID + j];
  __syncthreads();

  float ps = 0.f, hs = 0.f;
  const int chunk = NPG / RSPLIT;  // 125
  const int base = g * NPG + part * chunk;
  for (int n = 0; n < chunk; n += 2) {
    const bool valid = (n + sub) < chunk;
    if (valid) {
      const float x = Xr[(size_t)(base + n + sub) * HID + j];
      hrow[sub][j] = leaky(fmaf(aj, x, cj));
    }
    __syncthreads();
    if (valid) {
      float a0 = 0.f, a1 = 0.f, a2 = 0.f, a3 = 0.f;
#pragma unroll
      for (int k = 0; k < HID; k += 4) {
        a0 += hrow[sub][k + 0] * Wl[(k + 0) * HID + j];
        a1 += hrow[sub][k + 1] * Wl[(k + 1) * HID + j];
        a2 += hrow[sub][k + 2] * Wl[(k + 2) * HID + j];
        a3 += hrow[sub][k + 3] * Wl[(k + 3) * HID + j];
      }
      ps += leaky(bj + ((a0 + a1) + (a2 + a3)));
      hs += hrow[sub][j];
    }
    __syncthreads();
  }
  unsafeAtomicAdd(&phi_sum[g * HID + j], ps);
  unsafeAtomicAdd(&h_sum[g * HID + j], hs);
}

// ---------------------------------------------------------------------------
// Readout part 2.
// ---------------------------------------------------------------------------
__global__ __launch_bounds__(64) void finalize_k(const float* __restrict__ phi_sum,
                                                 const float* __restrict__ h_sum,
                                                 const float* __restrict__ w2,
                                                 const float* __restrict__ b2,
                                                 float* __restrict__ out,
                                                 int roff, int moff) {
  const int g = blockIdx.x;
  const int j = threadIdx.x;  // 0..63
  float acc = b2[j];
#pragma unroll 8
  for (int k = 0; k < HID; ++k)
    acc += (phi_sum[g * HID + k] * (1.0f / NPG)) * w2[k * RD + j];
  const float r = leaky(acc);
  out[g * 384 + roff + j] = leaky(r);
  out[g * 384 + moff + j] = leaky(h_sum[g * HID + j] * (1.0f / NPG));
  out[g * 384 + moff + 64 + j] = leaky(h_sum[g * HID + 64 + j] * (1.0f / NPG));
}

// ---------------------------------------------------------------------------
extern "C" void kernel_launch(void* const* d_in, const int* in_sizes, int n_in,
                              void* d_out, int out_size, void* d_ws, size_t ws_size,
                              hipStream_t stream) {
  const float* node_feats = (const float*)d_in[0];
  const float* ew   = (const float*)d_in[1];
  const float* W1   = (const float*)d_in[2];
  const float* W2   = (const float*)d_in[3];
  const float* g1a  = (const float*)d_in[4];
  const float* g1g  = (const float*)d_in[5];
  const float* g1b  = (const float*)d_in[6];
  const float* g2a  = (const float*)d_in[7];
  const float* g2g  = (const float*)d_in[8];
  const float* g2b  = (const float*)d_in[9];
  const float* r1w1 = (const float*)d_in[10];
  const float* r1b1 = (const float*)d_in[11];
  const float* r1w2 = (const float*)d_in[12];
  const float* r1b2 = (const float*)d_in[13];
  const float* r2w1 = (const float*)d_in[14];
  const float* r2b1 = (const float*)d_in[15];
  const float* r2w2 = (const float*)d_in[16];
  const float* r2b2 = (const float*)d_in[17];
  const int* src = (const int*)d_in[18];
  const int* dst = (const int*)d_in[19];
  float* out = (float*)d_out;

  // workspace layout (zeroed region first)
  char* wsb = (char*)d_ws;
  int*   cin     = (int*)wsb;                         // NN        } zeroed
  int*   cout_   = cin + NN;                          // NN        }
  float* ps1     = (float*)(cout_ + NN);              // NG*HID x8 }
  float* hs1     = ps1 + NG * HID;
  float* ps2     = hs1 + NG * HID;
  float* hs2     = ps2 + NG * HID;
  float* sx1     = hs2 + NG * HID;
  float* sq1     = sx1 + NG * HID;
  float* sx2     = sq1 + NG * HID;
  float* sq2     = sx2 + NG * HID;
  int*   offs    = (int*)(sq2 + NG * HID);            // NN
  int*   cursor  = offs + NN;                         // NN
  int*   csr_src = cursor + NN;                       // NE
  float* csr_w   = (float*)(csr_src + NE);            // NE
  float* A1      = csr_w + NE;                        // NG*HID x4
  float* B1      = A1 + NG * HID;
  float* A2      = B1 + NG * HID;
  float* B2      = A2 + NG * HID;
  float* bufA    = B2 + NG * HID;                     // NN*HID
  float* bufB    = bufA + (size_t)NN * HID;           // NN*HID

  const size_t zero_bytes = (size_t)(2 * NN) * sizeof(int) +
                            (size_t)(8 * NG * HID) * sizeof(float);
  hipMemsetAsync(d_ws, 0, zero_bytes, stream);

  // graph structure (rebuilt each call; ws is re-poisoned every launch)
  degrees_k<<<(NE + 255) / 256, 256, 0, stream>>>(src, dst, cout_, cin);
  scan_k<<<NG, 256, 0, stream>>>(cin, offs, cursor);
  csr_build_k<<<(NE + 255) / 256, 256, 0, stream>>>(src, dst, ew, cursor, csr_src, csr_w);

  // ---- layer 1 ----
  gemm1_k<<<(NN + 63) / 64, 256, 0, stream>>>(node_feats, W1, cout_, bufA);
  gather_k<<<NN / GSN, 256, 0, stream>>>(bufA, csr_src, csr_w, offs, cin, bufB, sx1, sq1);
  stats_k<<<NG, HID, 0, stream>>>(sx1, sq1, g1a, g1g, g1b, A1, B1);
  phi_pool_k<<<NG * RSPLIT, 256, 0, stream>>>(bufB, A1, B1, r1w1, r1b1, ps1, hs1);
  finalize_k<<<NG, 64, 0, stream>>>(ps1, hs1, r1w2, r1b2, out, 0, 64);

  // ---- layer 2 ----
  gemm_norm_k<<<(NN + 63) / 64, 256, 0, stream>>>(bufB, W2, A1, B1, cout_, bufA);
  gather_k<<<NN / GSN, 256, 0, stream>>>(bufA, csr_src, csr_w, offs, cin, bufB, sx2, sq2);
  stats_k<<<NG, HID, 0, stream>>>(sx2, sq2, g2a, g2g, g2b, A2, B2);
  phi_pool_k<<<NG * RSPLIT, 256, 0, stream>>>(bufB, A2, B2, r2w1, r2b1, ps2, hs2);
  finalize_k<<<NG, 64, 0, stream>>>(ps2, hs2, r2w2, r2b2, out, 192, 256);
}

// Round 4
// 716.132 us; speedup vs baseline: 10.2293x; 2.0868x over previous
//
#include <hip/hip_runtime.h>
#include <cstddef>
#include <cstdint>

#define NG   100
#define NPG  1000
#define NN   (NG * NPG)       // 100000 nodes
#define NE   (NN * 16)        // 1600000 edges
#define EPG  (NE / NG)        // 16000 edges per graph (edges are graph-local)
#define FIN  64
#define HID  128
#define RD   64
#define SLOPE 0.01f
#define EPSV  1e-5f
#define PHI_SPLIT 4
#define NSTRIP (NPG / PHI_SPLIT)  // 250 nodes per phi block
#define GSN   40              // nodes per gather block (40 | 1000 -> graph-aligned)
#define KP1   (FIN + 8)       // padded LDS k-stride (bf16 elems), K=64
#define KP2   (HID + 8)       // padded LDS k-stride, K=128

using short8 = __attribute__((ext_vector_type(8))) short;   // 8 bf16 = 4 VGPRs
using f32x4  = __attribute__((ext_vector_type(4))) float;

__device__ __forceinline__ float leaky(float x) { return x >= 0.f ? x : SLOPE * x; }

// fp32 -> bf16 (round-to-nearest-even), bit pattern
__device__ __forceinline__ unsigned short f2bf(float f) {
  union { float f; unsigned u; } v; v.f = f;
  return (unsigned short)((v.u + 0x7fffu + ((v.u >> 16) & 1u)) >> 16);
}

// ---------------------------------------------------------------------------
// Degree counts (int): out over src, in over dst.
// ---------------------------------------------------------------------------
__global__ __launch_bounds__(256) void degrees_k(const int* __restrict__ src,
                                                 const int* __restrict__ dst,
                                                 int* __restrict__ cout_,
                                                 int* __restrict__ cin_) {
  int e = blockIdx.x * 256 + threadIdx.x;
  if (e < NE) {
    atomicAdd(&cout_[src[e]], 1);
    atomicAdd(&cin_[dst[e]], 1);
  }
}

// ---------------------------------------------------------------------------
// Per-graph exclusive scan of in-degree counts -> CSR offsets + cursor copy.
// ---------------------------------------------------------------------------
__global__ __launch_bounds__(256) void scan_k(const int* __restrict__ cin_,
                                              int* __restrict__ offs,
                                              int* __restrict__ cursor) {
  __shared__ int tsum[256];
  const int g = blockIdx.x;
  const int t = threadIdx.x;
  const int base = g * NPG;
  int v[4];
  int loc = 0;
#pragma unroll
  for (int k = 0; k < 4; ++k) {
    const int idx = t * 4 + k;
    v[k] = (idx < NPG) ? cin_[base + idx] : 0;
    loc += v[k];
  }
  tsum[t] = loc;
  __syncthreads();
  for (int d = 1; d < 256; d <<= 1) {
    int x = (t >= d) ? tsum[t - d] : 0;
    __syncthreads();
    tsum[t] += x;
    __syncthreads();
  }
  int run = (t > 0 ? tsum[t - 1] : 0) + g * EPG;
#pragma unroll
  for (int k = 0; k < 4; ++k) {
    const int idx = t * 4 + k;
    if (idx < NPG) {
      offs[base + idx] = run;
      cursor[base + idx] = run;
      run += v[k];
    }
  }
}

// ---------------------------------------------------------------------------
// CSR build: slot each edge's (src, w) under its dst bucket.
// ---------------------------------------------------------------------------
__global__ __launch_bounds__(256) void csr_build_k(const int* __restrict__ src,
                                                   const int* __restrict__ dst,
                                                   const float* __restrict__ ew,
                                                   int* __restrict__ cursor,
                                                   int* __restrict__ csr_src,
                                                   float* __restrict__ csr_w) {
  int e = blockIdx.x * 256 + threadIdx.x;
  if (e < NE) {
    const int pos = atomicAdd(&cursor[dst[e]], 1);
    csr_src[pos] = src[e];
    csr_w[pos] = ew[e];
  }
}

// ---------------------------------------------------------------------------
// Layer-1 GEMM (MFMA bf16): Y[node][n] = out_isqrt * (X[node][:] @ W1)[n]
// 256 thr = 4 waves; per pass 64 rows; wave w owns rows [w*16, w*16+16).
// A-frag: A[m=lane&15][k=quad*8+j]; B-frag: B[k=quad*8+j][n=lane&15];
// C/D: col=lane&15, row=quad*4+reg (learn_hip m89-verified).
// ---------------------------------------------------------------------------
__global__ __launch_bounds__(256) void gemm1_k(const float* __restrict__ X,
                                               const float* __restrict__ W,
                                               const int* __restrict__ cout_,
                                               float* __restrict__ Y) {
  __shared__ unsigned short Xl[64 * KP1];
  __shared__ unsigned short Wl[HID * KP1];
  const int tid = threadIdx.x;
  const int wave = tid >> 6, lane = tid & 63, l15 = lane & 15, quad = lane >> 4;
  // stage W1 [64][128] fp32 -> Wl[n][k] bf16 (transposed)
  for (int i = tid; i < FIN * (HID / 4); i += 256) {
    const int k = i >> 5;      // 0..63
    const int nq = i & 31;
    const float4 w = *(const float4*)(W + (size_t)k * HID + nq * 4);
    Wl[(nq * 4 + 0) * KP1 + k] = f2bf(w.x);
    Wl[(nq * 4 + 1) * KP1 + k] = f2bf(w.y);
    Wl[(nq * 4 + 2) * KP1 + k] = f2bf(w.z);
    Wl[(nq * 4 + 3) * KP1 + k] = f2bf(w.w);
  }
  const int blkbase = blockIdx.x * 256;
  for (int pass = 0; pass < 4; ++pass) {
    __syncthreads();
    for (int i = tid; i < 64 * (FIN / 4); i += 256) {  // 1024
      const int r = i >> 4;
      const int kq = i & 15;
      const int node = blkbase + pass * 64 + r;
      ushort4 u = make_ushort4(0, 0, 0, 0);
      if (node < NN) {
        const float4 x = *(const float4*)(X + (size_t)node * FIN + kq * 4);
        u.x = f2bf(x.x); u.y = f2bf(x.y); u.z = f2bf(x.z); u.w = f2bf(x.w);
      }
      *(ushort4*)&Xl[r * KP1 + kq * 4] = u;
    }
    __syncthreads();
    short8 a[2];
#pragma unroll
    for (int kt = 0; kt < 2; ++kt)
      a[kt] = *(const short8*)&Xl[(wave * 16 + l15) * KP1 + kt * 32 + quad * 8];
    float sc[4];
    int nodes[4];
#pragma unroll
    for (int r = 0; r < 4; ++r) {
      nodes[r] = blkbase + pass * 64 + wave * 16 + quad * 4 + r;
      sc[r] = (nodes[r] < NN) ? rsqrtf(fmaxf((float)cout_[nodes[r]], 1.0f)) : 0.f;
    }
#pragma unroll
    for (int ct = 0; ct < 8; ++ct) {
      f32x4 acc = {0.f, 0.f, 0.f, 0.f};
#pragma unroll
      for (int kt = 0; kt < 2; ++kt) {
        const short8 b = *(const short8*)&Wl[(ct * 16 + l15) * KP1 + kt * 32 + quad * 8];
        acc = __builtin_amdgcn_mfma_f32_16x16x32_bf16(a[kt], b, acc, 0, 0, 0);
      }
      const int n = ct * 16 + l15;
#pragma unroll
      for (int r = 0; r < 4; ++r)
        if (nodes[r] < NN) Y[(size_t)nodes[r] * HID + n] = acc[r] * sc[r];
    }
  }
}

// ---------------------------------------------------------------------------
// Layer-2 GEMM (MFMA bf16) with fused GraphNorm apply on the input:
//   xn[k] = leaky(A[g][k]*X[node][k] + B[g][k]) staged as bf16,
//   Y[node][n] = out_isqrt * (xn @ W2)[n].
// ---------------------------------------------------------------------------
__global__ __launch_bounds__(256) void gemm_norm_k(const float* __restrict__ X,
                                                   const float* __restrict__ W,
                                                   const float* __restrict__ An,
                                                   const float* __restrict__ Bn,
                                                   const int* __restrict__ cout_,
                                                   float* __restrict__ Y) {
  __shared__ unsigned short Xl[64 * KP2];
  __shared__ unsigned short Wl[HID * KP2];
  const int tid = threadIdx.x;
  const int wave = tid >> 6, lane = tid & 63, l15 = lane & 15, quad = lane >> 4;
  for (int i = tid; i < HID * (HID / 4); i += 256) {
    const int k = i >> 5;      // 0..127
    const int nq = i & 31;
    const float4 w = *(const float4*)(W + (size_t)k * HID + nq * 4);
    Wl[(nq * 4 + 0) * KP2 + k] = f2bf(w.x);
    Wl[(nq * 4 + 1) * KP2 + k] = f2bf(w.y);
    Wl[(nq * 4 + 2) * KP2 + k] = f2bf(w.z);
    Wl[(nq * 4 + 3) * KP2 + k] = f2bf(w.w);
  }
  const int blkbase = blockIdx.x * 256;
  for (int pass = 0; pass < 4; ++pass) {
    __syncthreads();
    for (int i = tid; i < 64 * 32; i += 256) {
      const int r = i >> 5;
      const int kq = i & 31;
      const int node = blkbase + pass * 64 + r;
      ushort4 u = make_ushort4(0, 0, 0, 0);
      if (node < NN) {
        const int g = node / NPG;
        const float4 x = *(const float4*)(X + (size_t)node * HID + kq * 4);
        const float4 A4 = *(const float4*)(An + (size_t)g * HID + kq * 4);
        const float4 B4 = *(const float4*)(Bn + (size_t)g * HID + kq * 4);
        u.x = f2bf(leaky(fmaf(A4.x, x.x, B4.x)));
        u.y = f2bf(leaky(fmaf(A4.y, x.y, B4.y)));
        u.z = f2bf(leaky(fmaf(A4.z, x.z, B4.z)));
        u.w = f2bf(leaky(fmaf(A4.w, x.w, B4.w)));
      }
      *(ushort4*)&Xl[r * KP2 + kq * 4] = u;
    }
    __syncthreads();
    short8 a[4];
#pragma unroll
    for (int kt = 0; kt < 4; ++kt)
      a[kt] = *(const short8*)&Xl[(wave * 16 + l15) * KP2 + kt * 32 + quad * 8];
    float sc[4];
    int nodes[4];
#pragma unroll
    for (int r = 0; r < 4; ++r) {
      nodes[r] = blkbase + pass * 64 + wave * 16 + quad * 4 + r;
      sc[r] = (nodes[r] < NN) ? rsqrtf(fmaxf((float)cout_[nodes[r]], 1.0f)) : 0.f;
    }
#pragma unroll
    for (int ct = 0; ct < 8; ++ct) {
      f32x4 acc = {0.f, 0.f, 0.f, 0.f};
#pragma unroll
      for (int kt = 0; kt < 4; ++kt) {
        const short8 b = *(const short8*)&Wl[(ct * 16 + l15) * KP2 + kt * 32 + quad * 8];
        acc = __builtin_amdgcn_mfma_f32_16x16x32_bf16(a[kt], b, acc, 0, 0, 0);
      }
      const int n = ct * 16 + l15;
#pragma unroll
      for (int r = 0; r < 4; ++r)
        if (nodes[r] < NN) Y[(size_t)nodes[r] * HID + n] = acc[r] * sc[r];
    }
  }
}

// ---------------------------------------------------------------------------
// Readout phi+pool (MFMA bf16), fused norm apply:
//   xn = leaky(A*x+B) (staged, also pooled into h_sum),
//   pooled phi = sum_nodes leaky(xn @ w1 + b1) -> atomics into phi_sum.
// One block per (graph, 1/PHI_SPLIT strip of 250 nodes); 4 passes of 64 rows.
// ---------------------------------------------------------------------------
__global__ __launch_bounds__(256) void phi_pool_k(const float* __restrict__ Xr,
                                                  const float* __restrict__ An,
                                                  const float* __restrict__ Bn,
                                                  const float* __restrict__ w1,
                                                  const float* __restrict__ b1,
                                                  float* __restrict__ phi_sum,
                                                  float* __restrict__ h_sum) {
  __shared__ unsigned short Xl[64 * KP2];
  __shared__ unsigned short Wl[HID * KP2];
  __shared__ float red[16][HID];
  __shared__ float hred[8][HID];
  const int tid = threadIdx.x;
  const int wave = tid >> 6, lane = tid & 63, l15 = lane & 15, quad = lane >> 4;
  const int g = blockIdx.x / PHI_SPLIT;
  const int part = blockIdx.x % PHI_SPLIT;
  const int base = g * NPG + part * NSTRIP;

  for (int i = tid; i < HID * (HID / 4); i += 256) {
    const int k = i >> 5;
    const int nq = i & 31;
    const float4 w = *(const float4*)(w1 + (size_t)k * HID + nq * 4);
    Wl[(nq * 4 + 0) * KP2 + k] = f2bf(w.x);
    Wl[(nq * 4 + 1) * KP2 + k] = f2bf(w.y);
    Wl[(nq * 4 + 2) * KP2 + k] = f2bf(w.z);
    Wl[(nq * 4 + 3) * KP2 + k] = f2bf(w.w);
  }
  float bcol[8];
#pragma unroll
  for (int ct = 0; ct < 8; ++ct) bcol[ct] = b1[ct * 16 + l15];

  float pooled[8] = {0.f, 0.f, 0.f, 0.f, 0.f, 0.f, 0.f, 0.f};
  float hp[4] = {0.f, 0.f, 0.f, 0.f};

  for (int pass = 0; pass < 4; ++pass) {
    __syncthreads();
    for (int i = tid; i < 64 * 32; i += 256) {
      const int r = i >> 5;
      const int kq = i & 31;   // == tid&31 always (stride 256)
      const int rowi = pass * 64 + r;
      ushort4 u = make_ushort4(0, 0, 0, 0);
      if (rowi < NSTRIP) {
        const int node = base + rowi;
        const float4 x = *(const float4*)(Xr + (size_t)node * HID + kq * 4);
        const float4 A4 = *(const float4*)(An + (size_t)g * HID + kq * 4);
        const float4 B4 = *(const float4*)(Bn + (size_t)g * HID + kq * 4);
        const float x0 = leaky(fmaf(A4.x, x.x, B4.x));
        const float x1 = leaky(fmaf(A4.y, x.y, B4.y));
        const float x2 = leaky(fmaf(A4.z, x.z, B4.z));
        const float x3 = leaky(fmaf(A4.w, x.w, B4.w));
        hp[0] += x0; hp[1] += x1; hp[2] += x2; hp[3] += x3;
        u.x = f2bf(x0); u.y = f2bf(x1); u.z = f2bf(x2); u.w = f2bf(x3);
      }
      *(ushort4*)&Xl[r * KP2 + kq * 4] = u;
    }
    __syncthreads();
    short8 a[4];
#pragma unroll
    for (int kt = 0; kt < 4; ++kt)
      a[kt] = *(const short8*)&Xl[(wave * 16 + l15) * KP2 + kt * 32 + quad * 8];
#pragma unroll
    for (int ct = 0; ct < 8; ++ct) {
      f32x4 acc = {0.f, 0.f, 0.f, 0.f};
#pragma unroll
      for (int kt = 0; kt < 4; ++kt) {
        const short8 b = *(const short8*)&Wl[(ct * 16 + l15) * KP2 + kt * 32 + quad * 8];
        acc = __builtin_amdgcn_mfma_f32_16x16x32_bf16(a[kt], b, acc, 0, 0, 0);
      }
#pragma unroll
      for (int r = 0; r < 4; ++r) {
        const int rowi = pass * 64 + wave * 16 + quad * 4 + r;
        if (rowi < NSTRIP) pooled[ct] += leaky(acc[r] + bcol[ct]);
      }
    }
  }
  // block-level reduction: phi partials over (wave,quad), h partials over tid>>5
  const int qi = wave * 4 + quad;
#pragma unroll
  for (int ct = 0; ct < 8; ++ct) red[qi][ct * 16 + l15] = pooled[ct];
#pragma unroll
  for (int c = 0; c < 4; ++c) hred[tid >> 5][(tid & 31) * 4 + c] = hp[c];
  __syncthreads();
  if (tid < HID) {
    float s = 0.f;
#pragma unroll
    for (int q = 0; q < 16; ++q) s += red[q][tid];
    unsafeAtomicAdd(&phi_sum[g * HID + tid], s);
  } else {
    const int t = tid - HID;
    float s = 0.f;
#pragma unroll
    for (int rr = 0; rr < 8; ++rr) s += hred[rr][t];
    unsafeAtomicAdd(&h_sum[g * HID + t], s);
  }
}

// ---------------------------------------------------------------------------
// Atomic-free aggregation + in_isqrt + fused per-graph stats.
// ---------------------------------------------------------------------------
__global__ __launch_bounds__(256) void gather_k(const float* __restrict__ H,
                                                const int* __restrict__ csr_src,
                                                const float* __restrict__ csr_w,
                                                const int* __restrict__ offs,
                                                const int* __restrict__ cin_,
                                                float* __restrict__ AGG,
                                                float* __restrict__ sx,
                                                float* __restrict__ sq) {
  __shared__ float redx[4][HID];
  __shared__ float redq[4][HID];
  const int wave = threadIdx.x >> 6;
  const int lane = threadIdx.x & 63;
  const int base = blockIdx.x * GSN;
  const int g = base / NPG;

  float sxa = 0.f, sxb = 0.f, sqa = 0.f, sqb = 0.f;
  for (int n = base + wave; n < base + GSN; n += 4) {
    const int off = offs[n];
    const int cnt = cin_[n];
    const float isq = rsqrtf(fmaxf((float)cnt, 1.0f));
    float ax = 0.f, ay = 0.f, bx = 0.f, by = 0.f;
    int i = 0;
    for (; i + 2 <= cnt; i += 2) {
      const int s0 = csr_src[off + i];
      const int s1 = csr_src[off + i + 1];
      const float w0 = csr_w[off + i];
      const float w1 = csr_w[off + i + 1];
      const float2 v0 = *(const float2*)(H + (size_t)s0 * HID + lane * 2);
      const float2 v1 = *(const float2*)(H + (size_t)s1 * HID + lane * 2);
      ax += w0 * v0.x; ay += w0 * v0.y;
      bx += w1 * v1.x; by += w1 * v1.y;
    }
    if (i < cnt) {
      const int s0 = csr_src[off + i];
      const float w0 = csr_w[off + i];
      const float2 v0 = *(const float2*)(H + (size_t)s0 * HID + lane * 2);
      ax += w0 * v0.x; ay += w0 * v0.y;
    }
    float2 r;
    r.x = (ax + bx) * isq;
    r.y = (ay + by) * isq;
    *(float2*)(AGG + (size_t)n * HID + lane * 2) = r;
    sxa += r.x; sxb += r.y;
    sqa += r.x * r.x; sqb += r.y * r.y;
  }
  redx[wave][lane * 2] = sxa; redx[wave][lane * 2 + 1] = sxb;
  redq[wave][lane * 2] = sqa; redq[wave][lane * 2 + 1] = sqb;
  __syncthreads();
  const int tid = threadIdx.x;
  if (tid < HID) {
    unsafeAtomicAdd(&sx[g * HID + tid],
                    redx[0][tid] + redx[1][tid] + redx[2][tid] + redx[3][tid]);
  } else {
    const int t = tid - HID;
    unsafeAtomicAdd(&sq[g * HID + t],
                    redq[0][t] + redq[1][t] + redq[2][t] + redq[3][t]);
  }
}

// ---------------------------------------------------------------------------
// Fold stats into affine: normalized = A*x + B per (graph, feat).
// ---------------------------------------------------------------------------
__global__ __launch_bounds__(HID) void stats_k(const float* __restrict__ sx,
                                               const float* __restrict__ sq,
                                               const float* __restrict__ alpha,
                                               const float* __restrict__ gamma,
                                               const float* __restrict__ beta,
                                               float* __restrict__ An,
                                               float* __restrict__ Bn) {
  const int g = blockIdx.x;
  const int j = threadIdx.x;
  const float mean = sx[g * HID + j] * (1.0f / NPG);
  const float ex2 = sq[g * HID + j] * (1.0f / NPG);
  const float am = alpha[j] * mean;
  float var = ex2 - 2.0f * am * mean + am * am;
  var = fmaxf(var, 0.0f);
  const float rstd = rsqrtf(var + EPSV);
  const float A = gamma[j] * rstd;
  An[g * HID + j] = A;
  Bn[g * HID + j] = beta[j] - A * am;
}

// ---------------------------------------------------------------------------
// Readout part 2.
// ---------------------------------------------------------------------------
__global__ __launch_bounds__(64) void finalize_k(const float* __restrict__ phi_sum,
                                                 const float* __restrict__ h_sum,
                                                 const float* __restrict__ w2,
                                                 const float* __restrict__ b2,
                                                 float* __restrict__ out,
                                                 int roff, int moff) {
  const int g = blockIdx.x;
  const int j = threadIdx.x;  // 0..63
  float acc = b2[j];
#pragma unroll 8
  for (int k = 0; k < HID; ++k)
    acc += (phi_sum[g * HID + k] * (1.0f / NPG)) * w2[k * RD + j];
  const float r = leaky(acc);
  out[g * 384 + roff + j] = leaky(r);
  out[g * 384 + moff + j] = leaky(h_sum[g * HID + j] * (1.0f / NPG));
  out[g * 384 + moff + 64 + j] = leaky(h_sum[g * HID + 64 + j] * (1.0f / NPG));
}

// ---------------------------------------------------------------------------
extern "C" void kernel_launch(void* const* d_in, const int* in_sizes, int n_in,
                              void* d_out, int out_size, void* d_ws, size_t ws_size,
                              hipStream_t stream) {
  const float* node_feats = (const float*)d_in[0];
  const float* ew   = (const float*)d_in[1];
  const float* W1   = (const float*)d_in[2];
  const float* W2   = (const float*)d_in[3];
  const float* g1a  = (const float*)d_in[4];
  const float* g1g  = (const float*)d_in[5];
  const float* g1b  = (const float*)d_in[6];
  const float* g2a  = (const float*)d_in[7];
  const float* g2g  = (const float*)d_in[8];
  const float* g2b  = (const float*)d_in[9];
  const float* r1w1 = (const float*)d_in[10];
  const float* r1b1 = (const float*)d_in[11];
  const float* r1w2 = (const float*)d_in[12];
  const float* r1b2 = (const float*)d_in[13];
  const float* r2w1 = (const float*)d_in[14];
  const float* r2b1 = (const float*)d_in[15];
  const float* r2w2 = (const float*)d_in[16];
  const float* r2b2 = (const float*)d_in[17];
  const int* src = (const int*)d_in[18];
  const int* dst = (const int*)d_in[19];
  float* out = (float*)d_out;

  // workspace layout (zeroed region first)
  char* wsb = (char*)d_ws;
  int*   cin     = (int*)wsb;                         // NN        } zeroed
  int*   cout_   = cin + NN;                          // NN        }
  float* ps1     = (float*)(cout_ + NN);              // NG*HID x8 }
  float* hs1     = ps1 + NG * HID;
  float* ps2     = hs1 + NG * HID;
  float* hs2     = ps2 + NG * HID;
  float* sx1     = hs2 + NG * HID;
  float* sq1     = sx1 + NG * HID;
  float* sx2     = sq1 + NG * HID;
  float* sq2     = sx2 + NG * HID;
  int*   offs    = (int*)(sq2 + NG * HID);            // NN
  int*   cursor  = offs + NN;                         // NN
  int*   csr_src = cursor + NN;                       // NE
  float* csr_w   = (float*)(csr_src + NE);            // NE
  float* A1      = csr_w + NE;                        // NG*HID x4
  float* B1      = A1 + NG * HID;
  float* A2      = B1 + NG * HID;
  float* B2      = A2 + NG * HID;
  float* bufA    = B2 + NG * HID;                     // NN*HID
  float* bufB    = bufA + (size_t)NN * HID;           // NN*HID

  const size_t zero_bytes = (size_t)(2 * NN) * sizeof(int) +
                            (size_t)(8 * NG * HID) * sizeof(float);
  hipMemsetAsync(d_ws, 0, zero_bytes, stream);

  // graph structure (rebuilt each call; ws is re-poisoned every launch)
  degrees_k<<<(NE + 255) / 256, 256, 0, stream>>>(src, dst, cout_, cin);
  scan_k<<<NG, 256, 0, stream>>>(cin, offs, cursor);
  csr_build_k<<<(NE + 255) / 256, 256, 0, stream>>>(src, dst, ew, cursor, csr_src, csr_w);

  const int gemm_blocks = (NN + 255) / 256;  // 391, 4 passes of 64 rows each

  // ---- layer 1 ----
  gemm1_k<<<gemm_blocks, 256, 0, stream>>>(node_feats, W1, cout_, bufA);
  gather_k<<<NN / GSN, 256, 0, stream>>>(bufA, csr_src, csr_w, offs, cin, bufB, sx1, sq1);
  stats_k<<<NG, HID, 0, stream>>>(sx1, sq1, g1a, g1g, g1b, A1, B1);
  phi_pool_k<<<NG * PHI_SPLIT, 256, 0, stream>>>(bufB, A1, B1, r1w1, r1b1, ps1, hs1);
  finalize_k<<<NG, 64, 0, stream>>>(ps1, hs1, r1w2, r1b2, out, 0, 64);

  // ---- layer 2 ----
  gemm_norm_k<<<gemm_blocks, 256, 0, stream>>>(bufB, W2, A1, B1, cout_, bufA);
  gather_k<<<NN / GSN, 256, 0, stream>>>(bufA, csr_src, csr_w, offs, cin, bufB, sx2, sq2);
  stats_k<<<NG, HID, 0, stream>>>(sx2, sq2, g2a, g2g, g2b, A2, B2);
  phi_pool_k<<<NG * PHI_SPLIT, 256, 0, stream>>>(bufB, A2, B2, r2w1, r2b1, ps2, hs2);
  finalize_k<<<NG, 64, 0, stream>>>(ps2, hs2, r2w2, r2b2, out, 192, 256);
}

// Round 5
// 555.751 us; speedup vs baseline: 13.1814x; 1.2886x over previous
//
#include <hip/hip_runtime.h>
#include <cstddef>
#include <cstdint>

#define NG   100
#define NPG  1000
#define NN   (NG * NPG)       // 100000 nodes
#define NE   (NN * 16)        // 1600000 edges
#define EPG  (NE / NG)        // 16000 edges per graph (edges are graph-local)
#define FIN  64
#define HID  128
#define RD   64
#define SLOPE 0.01f
#define EPSV  1e-5f
#define NSTRIP 250            // nodes per GEMM/phi block (4 strips per graph)
#define GSN   40              // nodes per gather block (25 strips per graph)

using short8 = __attribute__((ext_vector_type(8))) short;   // 8 bf16 = 4 VGPRs
using f32x4  = __attribute__((ext_vector_type(4))) float;

__device__ __forceinline__ float leaky(float x) { return x >= 0.f ? x : SLOPE * x; }

// fp32 -> bf16 (round-to-nearest-even), bit pattern
__device__ __forceinline__ unsigned short f2bf(float f) {
  union { float f; unsigned u; } v; v.f = f;
  return (unsigned short)((v.u + 0x7fffu + ((v.u >> 16) & 1u)) >> 16);
}

// XCD-affinity swizzle: heuristic block->XCD map is blockIdx%8. Pin graph g
// to XCD g%8 so producer/consumer blocks of one graph share an L2.
// grid must be 8 * per_g * 13; returns false for padding blocks.
__device__ __forceinline__ bool swz(int b, int per_g, int& g, int& part) {
  const int xcd = b & 7;
  const int slot = b >> 3;
  g = xcd + 8 * (slot / per_g);
  part = slot % per_g;
  return g < NG;
}

// ---------------------------------------------------------------------------
// One-shot bf16 transpose of the four GEMM weight matrices: Wt[n][k]=W[k][n].
// ---------------------------------------------------------------------------
__global__ __launch_bounds__(256) void wt_k(const float* __restrict__ W1,
                                            const float* __restrict__ W2,
                                            const float* __restrict__ R1,
                                            const float* __restrict__ R2,
                                            unsigned short* __restrict__ Wt1,
                                            unsigned short* __restrict__ Wt2,
                                            unsigned short* __restrict__ Rt1,
                                            unsigned short* __restrict__ Rt2) {
  const int idx = blockIdx.x * 256 + threadIdx.x;  // 57344 total
  if (idx < FIN * HID) {
    const int n = idx >> 6, k = idx & 63;          // Wt1 [128][64]
    Wt1[idx] = f2bf(W1[k * HID + n]);
  } else {
    const int j = idx - FIN * HID;
    const int m = j >> 14, r = j & 16383;
    const int n = r >> 7, k = r & 127;
    const float* s = (m == 0) ? W2 : (m == 1) ? R1 : R2;
    unsigned short* d = (m == 0) ? Wt2 : (m == 1) ? Rt1 : Rt2;
    d[r] = f2bf(s[k * HID + n]);
  }
}

// ---------------------------------------------------------------------------
// Degree counts (int): out over src, in over dst.
// ---------------------------------------------------------------------------
__global__ __launch_bounds__(256) void degrees_k(const int* __restrict__ src,
                                                 const int* __restrict__ dst,
                                                 int* __restrict__ cout_,
                                                 int* __restrict__ cin_) {
  int e = blockIdx.x * 256 + threadIdx.x;
  if (e < NE) {
    atomicAdd(&cout_[src[e]], 1);
    atomicAdd(&cin_[dst[e]], 1);
  }
}

// ---------------------------------------------------------------------------
// Per-graph exclusive scan of in-degree counts -> CSR offsets + cursor copy.
// ---------------------------------------------------------------------------
__global__ __launch_bounds__(256) void scan_k(const int* __restrict__ cin_,
                                              int* __restrict__ offs,
                                              int* __restrict__ cursor) {
  __shared__ int tsum[256];
  const int g = blockIdx.x;
  const int t = threadIdx.x;
  const int base = g * NPG;
  int v[4];
  int loc = 0;
#pragma unroll
  for (int k = 0; k < 4; ++k) {
    const int idx = t * 4 + k;
    v[k] = (idx < NPG) ? cin_[base + idx] : 0;
    loc += v[k];
  }
  tsum[t] = loc;
  __syncthreads();
  for (int d = 1; d < 256; d <<= 1) {
    int x = (t >= d) ? tsum[t - d] : 0;
    __syncthreads();
    tsum[t] += x;
    __syncthreads();
  }
  int run = (t > 0 ? tsum[t - 1] : 0) + g * EPG;
#pragma unroll
  for (int k = 0; k < 4; ++k) {
    const int idx = t * 4 + k;
    if (idx < NPG) {
      offs[base + idx] = run;
      cursor[base + idx] = run;
      run += v[k];
    }
  }
}

// ---------------------------------------------------------------------------
// CSR build: slot each edge's (src, w) under its dst bucket.
// ---------------------------------------------------------------------------
__global__ __launch_bounds__(256) void csr_build_k(const int* __restrict__ src,
                                                   const int* __restrict__ dst,
                                                   const float* __restrict__ ew,
                                                   int* __restrict__ cursor,
                                                   int* __restrict__ csr_src,
                                                   float* __restrict__ csr_w) {
  int e = blockIdx.x * 256 + threadIdx.x;
  if (e < NE) {
    const int pos = atomicAdd(&cursor[dst[e]], 1);
    csr_src[pos] = src[e];
    csr_w[pos] = ew[e];
  }
}

// ---------------------------------------------------------------------------
// Layer-1 GEMM (MFMA bf16), XCD-swizzled, 250-row strips.
// LDS layout: unpadded rows, 8-bf16 chunks XOR-swizzled by (row & mask):
// physical chunk = c ^ (row & (CH-1)) -> all reads/writes <=2-way conflicts.
// A-frag A[m=lane&15][k=quad*8+j]; B-frag B[k=quad*8+j][n=lane&15];
// C/D col=lane&15, row=quad*4+reg (m89-verified).
// ---------------------------------------------------------------------------
__global__ __launch_bounds__(256) void gemm1_k(const float* __restrict__ X,
                                               const unsigned short* __restrict__ Wt,
                                               const int* __restrict__ cout_,
                                               float* __restrict__ Y) {
  __shared__ unsigned short Xl[64 * FIN];
  __shared__ unsigned short Wl[HID * FIN];
  const int tid = threadIdx.x;
  const int wave = tid >> 6, lane = tid & 63, l15 = lane & 15, quad = lane >> 4;
  int g, part;
  if (!swz(blockIdx.x, 4, g, part)) return;
  const int base = g * NPG + part * NSTRIP;

  // stage Wt [128][64] bf16 -> swizzled LDS, 16B chunks, coalesced
  for (int i = tid; i < HID * (FIN / 8); i += 256) {  // 1024 chunks
    const int n = i >> 3, c = i & 7;
    const short8 w = *(const short8*)(Wt + n * FIN + c * 8);
    *(short8*)&Wl[n * FIN + ((c ^ (n & 7)) << 3)] = w;
  }
  for (int pass = 0; pass < 4; ++pass) {
    __syncthreads();
    for (int i = tid; i < 64 * (FIN / 4); i += 256) {  // 1024
      const int r = i >> 4;
      const int kq = i & 15;
      const int rowi = pass * 64 + r;
      ushort4 u = make_ushort4(0, 0, 0, 0);
      if (rowi < NSTRIP) {
        const float4 x = *(const float4*)(X + (size_t)(base + rowi) * FIN + kq * 4);
        u.x = f2bf(x.x); u.y = f2bf(x.y); u.z = f2bf(x.z); u.w = f2bf(x.w);
      }
      const int c = kq >> 1, half = kq & 1;
      *(ushort4*)&Xl[r * FIN + (((c ^ (r & 7)) << 3) | (half << 2))] = u;
    }
    __syncthreads();
    short8 a[2];
    const int arow = wave * 16 + l15;
#pragma unroll
    for (int kt = 0; kt < 2; ++kt)
      a[kt] = *(const short8*)&Xl[arow * FIN + (((kt * 4 + quad) ^ (l15 & 7)) << 3)];
    float sc[4];
    int rows[4];
#pragma unroll
    for (int r = 0; r < 4; ++r) {
      rows[r] = pass * 64 + wave * 16 + quad * 4 + r;
      sc[r] = (rows[r] < NSTRIP) ? rsqrtf(fmaxf((float)cout_[base + rows[r]], 1.0f)) : 0.f;
    }
#pragma unroll
    for (int ct = 0; ct < 8; ++ct) {
      f32x4 acc = {0.f, 0.f, 0.f, 0.f};
      const int brow = ct * 16 + l15;
#pragma unroll
      for (int kt = 0; kt < 2; ++kt) {
        const short8 b = *(const short8*)&Wl[brow * FIN + (((kt * 4 + quad) ^ (l15 & 7)) << 3)];
        acc = __builtin_amdgcn_mfma_f32_16x16x32_bf16(a[kt], b, acc, 0, 0, 0);
      }
      const int n = ct * 16 + l15;
#pragma unroll
      for (int r = 0; r < 4; ++r)
        if (rows[r] < NSTRIP) Y[(size_t)(base + rows[r]) * HID + n] = acc[r] * sc[r];
    }
  }
}

// ---------------------------------------------------------------------------
// Layer-2 GEMM (MFMA bf16) with fused GraphNorm apply, XCD-swizzled.
// ---------------------------------------------------------------------------
__global__ __launch_bounds__(256) void gemm_norm_k(const float* __restrict__ X,
                                                   const unsigned short* __restrict__ Wt,
                                                   const float* __restrict__ An,
                                                   const float* __restrict__ Bn,
                                                   const int* __restrict__ cout_,
                                                   float* __restrict__ Y) {
  __shared__ unsigned short Xl[64 * HID];
  __shared__ unsigned short Wl[HID * HID];
  const int tid = threadIdx.x;
  const int wave = tid >> 6, lane = tid & 63, l15 = lane & 15, quad = lane >> 4;
  int g, part;
  if (!swz(blockIdx.x, 4, g, part)) return;
  const int base = g * NPG + part * NSTRIP;

  for (int i = tid; i < HID * (HID / 8); i += 256) {  // 2048 chunks
    const int n = i >> 4, c = i & 15;
    const short8 w = *(const short8*)(Wt + n * HID + c * 8);
    *(short8*)&Wl[n * HID + ((c ^ (n & 15)) << 3)] = w;
  }
  for (int pass = 0; pass < 4; ++pass) {
    __syncthreads();
    for (int i = tid; i < 64 * 32; i += 256) {
      const int r = i >> 5;
      const int kq = i & 31;
      const int rowi = pass * 64 + r;
      ushort4 u = make_ushort4(0, 0, 0, 0);
      if (rowi < NSTRIP) {
        const int node = base + rowi;
        const float4 x = *(const float4*)(X + (size_t)node * HID + kq * 4);
        const float4 A4 = *(const float4*)(An + (size_t)g * HID + kq * 4);
        const float4 B4 = *(const float4*)(Bn + (size_t)g * HID + kq * 4);
        u.x = f2bf(leaky(fmaf(A4.x, x.x, B4.x)));
        u.y = f2bf(leaky(fmaf(A4.y, x.y, B4.y)));
        u.z = f2bf(leaky(fmaf(A4.z, x.z, B4.z)));
        u.w = f2bf(leaky(fmaf(A4.w, x.w, B4.w)));
      }
      const int c = kq >> 1, half = kq & 1;
      *(ushort4*)&Xl[r * HID + (((c ^ (r & 15)) << 3) | (half << 2))] = u;
    }
    __syncthreads();
    short8 a[4];
    const int arow = wave * 16 + l15;
#pragma unroll
    for (int kt = 0; kt < 4; ++kt)
      a[kt] = *(const short8*)&Xl[arow * HID + (((kt * 4 + quad) ^ l15) << 3)];
    float sc[4];
    int rows[4];
#pragma unroll
    for (int r = 0; r < 4; ++r) {
      rows[r] = pass * 64 + wave * 16 + quad * 4 + r;
      sc[r] = (rows[r] < NSTRIP) ? rsqrtf(fmaxf((float)cout_[base + rows[r]], 1.0f)) : 0.f;
    }
#pragma unroll
    for (int ct = 0; ct < 8; ++ct) {
      f32x4 acc = {0.f, 0.f, 0.f, 0.f};
      const int brow = ct * 16 + l15;
#pragma unroll
      for (int kt = 0; kt < 4; ++kt) {
        const short8 b = *(const short8*)&Wl[brow * HID + (((kt * 4 + quad) ^ l15) << 3)];
        acc = __builtin_amdgcn_mfma_f32_16x16x32_bf16(a[kt], b, acc, 0, 0, 0);
      }
      const int n = ct * 16 + l15;
#pragma unroll
      for (int r = 0; r < 4; ++r)
        if (rows[r] < NSTRIP) Y[(size_t)(base + rows[r]) * HID + n] = acc[r] * sc[r];
    }
  }
}

// ---------------------------------------------------------------------------
// Readout phi+pool (MFMA bf16), fused norm apply, XCD-swizzled.
// ---------------------------------------------------------------------------
__global__ __launch_bounds__(256) void phi_pool_k(const float* __restrict__ Xr,
                                                  const float* __restrict__ An,
                                                  const float* __restrict__ Bn,
                                                  const unsigned short* __restrict__ Wt,
                                                  const float* __restrict__ b1,
                                                  float* __restrict__ phi_sum,
                                                  float* __restrict__ h_sum) {
  __shared__ unsigned short Xl[64 * HID];
  __shared__ unsigned short Wl[HID * HID];
  __shared__ float red[16][HID];
  __shared__ float hred[8][HID];
  const int tid = threadIdx.x;
  const int wave = tid >> 6, lane = tid & 63, l15 = lane & 15, quad = lane >> 4;
  int g, part;
  if (!swz(blockIdx.x, 4, g, part)) return;
  const int base = g * NPG + part * NSTRIP;

  for (int i = tid; i < HID * (HID / 8); i += 256) {
    const int n = i >> 4, c = i & 15;
    const short8 w = *(const short8*)(Wt + n * HID + c * 8);
    *(short8*)&Wl[n * HID + ((c ^ (n & 15)) << 3)] = w;
  }
  float bcol[8];
#pragma unroll
  for (int ct = 0; ct < 8; ++ct) bcol[ct] = b1[ct * 16 + l15];

  float pooled[8] = {0.f, 0.f, 0.f, 0.f, 0.f, 0.f, 0.f, 0.f};
  float hp[4] = {0.f, 0.f, 0.f, 0.f};

  for (int pass = 0; pass < 4; ++pass) {
    __syncthreads();
    for (int i = tid; i < 64 * 32; i += 256) {
      const int r = i >> 5;
      const int kq = i & 31;   // == tid&31 (stride 256)
      const int rowi = pass * 64 + r;
      ushort4 u = make_ushort4(0, 0, 0, 0);
      if (rowi < NSTRIP) {
        const int node = base + rowi;
        const float4 x = *(const float4*)(Xr + (size_t)node * HID + kq * 4);
        const float4 A4 = *(const float4*)(An + (size_t)g * HID + kq * 4);
        const float4 B4 = *(const float4*)(Bn + (size_t)g * HID + kq * 4);
        const float x0 = leaky(fmaf(A4.x, x.x, B4.x));
        const float x1 = leaky(fmaf(A4.y, x.y, B4.y));
        const float x2 = leaky(fmaf(A4.z, x.z, B4.z));
        const float x3 = leaky(fmaf(A4.w, x.w, B4.w));
        hp[0] += x0; hp[1] += x1; hp[2] += x2; hp[3] += x3;
        u.x = f2bf(x0); u.y = f2bf(x1); u.z = f2bf(x2); u.w = f2bf(x3);
      }
      const int c = kq >> 1, half = kq & 1;
      *(ushort4*)&Xl[r * HID + (((c ^ (r & 15)) << 3) | (half << 2))] = u;
    }
    __syncthreads();
    short8 a[4];
    const int arow = wave * 16 + l15;
#pragma unroll
    for (int kt = 0; kt < 4; ++kt)
      a[kt] = *(const short8*)&Xl[arow * HID + (((kt * 4 + quad) ^ l15) << 3)];
#pragma unroll
    for (int ct = 0; ct < 8; ++ct) {
      f32x4 acc = {0.f, 0.f, 0.f, 0.f};
      const int brow = ct * 16 + l15;
#pragma unroll
      for (int kt = 0; kt < 4; ++kt) {
        const short8 b = *(const short8*)&Wl[brow * HID + (((kt * 4 + quad) ^ l15) << 3)];
        acc = __builtin_amdgcn_mfma_f32_16x16x32_bf16(a[kt], b, acc, 0, 0, 0);
      }
#pragma unroll
      for (int r = 0; r < 4; ++r) {
        const int rowi = pass * 64 + wave * 16 + quad * 4 + r;
        if (rowi < NSTRIP) pooled[ct] += leaky(acc[r] + bcol[ct]);
      }
    }
  }
  const int qi = wave * 4 + quad;
#pragma unroll
  for (int ct = 0; ct < 8; ++ct) red[qi][ct * 16 + l15] = pooled[ct];
#pragma unroll
  for (int c = 0; c < 4; ++c) hred[tid >> 5][(tid & 31) * 4 + c] = hp[c];
  __syncthreads();
  if (tid < HID) {
    float s = 0.f;
#pragma unroll
    for (int q = 0; q < 16; ++q) s += red[q][tid];
    unsafeAtomicAdd(&phi_sum[g * HID + tid], s);
  } else {
    const int t = tid - HID;
    float s = 0.f;
#pragma unroll
    for (int rr = 0; rr < 8; ++rr) s += hred[rr][t];
    unsafeAtomicAdd(&h_sum[g * HID + t], s);
  }
}

// ---------------------------------------------------------------------------
// Atomic-free aggregation + in_isqrt + fused per-graph stats, XCD-swizzled.
// Per node: prefetch up to 64 (src,w) pairs with one coalesced load, then
// broadcast via shuffles so the row loads pipeline.
// ---------------------------------------------------------------------------
__global__ __launch_bounds__(256) void gather_k(const float* __restrict__ H,
                                                const int* __restrict__ csr_src,
                                                const float* __restrict__ csr_w,
                                                const int* __restrict__ offs,
                                                const int* __restrict__ cin_,
                                                float* __restrict__ AGG,
                                                float* __restrict__ sx,
                                                float* __restrict__ sq) {
  __shared__ float redx[4][HID];
  __shared__ float redq[4][HID];
  const int wave = threadIdx.x >> 6;
  const int lane = threadIdx.x & 63;
  int g, part;
  if (!swz(blockIdx.x, 25, g, part)) return;
  const int base = g * NPG + part * GSN;

  float sxa = 0.f, sxb = 0.f, sqa = 0.f, sqb = 0.f;
  for (int n = base + wave; n < base + GSN; n += 4) {
    const int off = offs[n];
    const int cnt = cin_[n];
    const float isq = rsqrtf(fmaxf((float)cnt, 1.0f));
    float ax = 0.f, ay = 0.f, bx = 0.f, by = 0.f;
    int i = 0;
    while (i < cnt) {
      const int take = min(cnt - i, 64);
      int sv = 0; float wv = 0.f;
      if (lane < take) {
        sv = csr_src[off + i + lane];
        wv = csr_w[off + i + lane];
      }
      int t = 0;
      for (; t + 2 <= take; t += 2) {
        const int s0 = __shfl(sv, t);
        const int s1 = __shfl(sv, t + 1);
        const float w0 = __shfl(wv, t);
        const float w1 = __shfl(wv, t + 1);
        const float2 v0 = *(const float2*)(H + (size_t)s0 * HID + lane * 2);
        const float2 v1 = *(const float2*)(H + (size_t)s1 * HID + lane * 2);
        ax = fmaf(w0, v0.x, ax); ay = fmaf(w0, v0.y, ay);
        bx = fmaf(w1, v1.x, bx); by = fmaf(w1, v1.y, by);
      }
      if (t < take) {
        const int s0 = __shfl(sv, t);
        const float w0 = __shfl(wv, t);
        const float2 v0 = *(const float2*)(H + (size_t)s0 * HID + lane * 2);
        ax = fmaf(w0, v0.x, ax); ay = fmaf(w0, v0.y, ay);
      }
      i += take;
    }
    float2 r;
    r.x = (ax + bx) * isq;
    r.y = (ay + by) * isq;
    *(float2*)(AGG + (size_t)n * HID + lane * 2) = r;
    sxa += r.x; sxb += r.y;
    sqa += r.x * r.x; sqb += r.y * r.y;
  }
  redx[wave][lane * 2] = sxa; redx[wave][lane * 2 + 1] = sxb;
  redq[wave][lane * 2] = sqa; redq[wave][lane * 2 + 1] = sqb;
  __syncthreads();
  const int tid = threadIdx.x;
  if (tid < HID) {
    unsafeAtomicAdd(&sx[g * HID + tid],
                    redx[0][tid] + redx[1][tid] + redx[2][tid] + redx[3][tid]);
  } else {
    const int t = tid - HID;
    unsafeAtomicAdd(&sq[g * HID + t],
                    redq[0][t] + redq[1][t] + redq[2][t] + redq[3][t]);
  }
}

// ---------------------------------------------------------------------------
// Fold stats into affine: normalized = A*x + B per (graph, feat).
// ---------------------------------------------------------------------------
__global__ __launch_bounds__(HID) void stats_k(const float* __restrict__ sx,
                                               const float* __restrict__ sq,
                                               const float* __restrict__ alpha,
                                               const float* __restrict__ gamma,
                                               const float* __restrict__ beta,
                                               float* __restrict__ An,
                                               float* __restrict__ Bn) {
  const int g = (blockIdx.x & 7) + 8 * (blockIdx.x >> 3);
  if (g >= NG) return;
  const int j = threadIdx.x;
  const float mean = sx[g * HID + j] * (1.0f / NPG);
  const float ex2 = sq[g * HID + j] * (1.0f / NPG);
  const float am = alpha[j] * mean;
  float var = ex2 - 2.0f * am * mean + am * am;
  var = fmaxf(var, 0.0f);
  const float rstd = rsqrtf(var + EPSV);
  const float A = gamma[j] * rstd;
  An[g * HID + j] = A;
  Bn[g * HID + j] = beta[j] - A * am;
}

// ---------------------------------------------------------------------------
// Readout part 2.
// ---------------------------------------------------------------------------
__global__ __launch_bounds__(64) void finalize_k(const float* __restrict__ phi_sum,
                                                 const float* __restrict__ h_sum,
                                                 const float* __restrict__ w2,
                                                 const float* __restrict__ b2,
                                                 float* __restrict__ out,
                                                 int roff, int moff) {
  const int g = blockIdx.x;
  const int j = threadIdx.x;  // 0..63
  float acc = b2[j];
#pragma unroll 8
  for (int k = 0; k < HID; ++k)
    acc += (phi_sum[g * HID + k] * (1.0f / NPG)) * w2[k * RD + j];
  const float r = leaky(acc);
  out[g * 384 + roff + j] = leaky(r);
  out[g * 384 + moff + j] = leaky(h_sum[g * HID + j] * (1.0f / NPG));
  out[g * 384 + moff + 64 + j] = leaky(h_sum[g * HID + 64 + j] * (1.0f / NPG));
}

// ---------------------------------------------------------------------------
extern "C" void kernel_launch(void* const* d_in, const int* in_sizes, int n_in,
                              void* d_out, int out_size, void* d_ws, size_t ws_size,
                              hipStream_t stream) {
  const float* node_feats = (const float*)d_in[0];
  const float* ew   = (const float*)d_in[1];
  const float* W1   = (const float*)d_in[2];
  const float* W2   = (const float*)d_in[3];
  const float* g1a  = (const float*)d_in[4];
  const float* g1g  = (const float*)d_in[5];
  const float* g1b  = (const float*)d_in[6];
  const float* g2a  = (const float*)d_in[7];
  const float* g2g  = (const float*)d_in[8];
  const float* g2b  = (const float*)d_in[9];
  const float* r1w1 = (const float*)d_in[10];
  const float* r1b1 = (const float*)d_in[11];
  const float* r1w2 = (const float*)d_in[12];
  const float* r1b2 = (const float*)d_in[13];
  const float* r2w1 = (const float*)d_in[14];
  const float* r2b1 = (const float*)d_in[15];
  const float* r2w2 = (const float*)d_in[16];
  const float* r2b2 = (const float*)d_in[17];
  const int* src = (const int*)d_in[18];
  const int* dst = (const int*)d_in[19];
  float* out = (float*)d_out;

  // workspace layout (zeroed region first)
  char* wsb = (char*)d_ws;
  int*   cin     = (int*)wsb;                         // NN        } zeroed
  int*   cout_   = cin + NN;                          // NN        }
  float* ps1     = (float*)(cout_ + NN);              // NG*HID x8 }
  float* hs1     = ps1 + NG * HID;
  float* ps2     = hs1 + NG * HID;
  float* hs2     = ps2 + NG * HID;
  float* sx1     = hs2 + NG * HID;
  float* sq1     = sx1 + NG * HID;
  float* sx2     = sq1 + NG * HID;
  float* sq2     = sx2 + NG * HID;
  int*   offs    = (int*)(sq2 + NG * HID);            // NN
  int*   cursor  = offs + NN;                         // NN
  int*   csr_src = cursor + NN;                       // NE
  float* csr_w   = (float*)(csr_src + NE);            // NE
  float* A1      = csr_w + NE;                        // NG*HID x4
  float* B1      = A1 + NG * HID;
  float* A2      = B1 + NG * HID;
  float* B2      = A2 + NG * HID;
  unsigned short* Wt1 = (unsigned short*)(B2 + NG * HID);  // 128*64
  unsigned short* Wt2 = Wt1 + HID * FIN;                   // 128*128
  unsigned short* Rt1 = Wt2 + HID * HID;
  unsigned short* Rt2 = Rt1 + HID * HID;
  float* bufA    = (float*)(Rt2 + HID * HID);         // NN*HID
  float* bufB    = bufA + (size_t)NN * HID;           // NN*HID

  const size_t zero_bytes = (size_t)(2 * NN) * sizeof(int) +
                            (size_t)(8 * NG * HID) * sizeof(float);
  hipMemsetAsync(d_ws, 0, zero_bytes, stream);

  // one-shot weight transpose to bf16
  wt_k<<<(FIN * HID + 3 * HID * HID) / 256, 256, 0, stream>>>(
      W1, W2, r1w1, r2w1, Wt1, Wt2, Rt1, Rt2);

  // graph structure (rebuilt each call; ws is re-poisoned every launch)
  degrees_k<<<(NE + 255) / 256, 256, 0, stream>>>(src, dst, cout_, cin);
  scan_k<<<NG, 256, 0, stream>>>(cin, offs, cursor);
  csr_build_k<<<(NE + 255) / 256, 256, 0, stream>>>(src, dst, ew, cursor, csr_src, csr_w);

  const int gemm_grid = 8 * 4 * 13;     // XCD-swizzled, 4 strips/graph
  const int gather_grid = 8 * 25 * 13;  // XCD-swizzled, 25 strips/graph
  const int stats_grid = 8 * 13;

  // ---- layer 1 ----
  gemm1_k<<<gemm_grid, 256, 0, stream>>>(node_feats, Wt1, cout_, bufA);
  gather_k<<<gather_grid, 256, 0, stream>>>(bufA, csr_src, csr_w, offs, cin, bufB, sx1, sq1);
  stats_k<<<stats_grid, HID, 0, stream>>>(sx1, sq1, g1a, g1g, g1b, A1, B1);
  phi_pool_k<<<gemm_grid, 256, 0, stream>>>(bufB, A1, B1, Rt1, r1b1, ps1, hs1);
  finalize_k<<<NG, 64, 0, stream>>>(ps1, hs1, r1w2, r1b2, out, 0, 64);

  // ---- layer 2 ----
  gemm_norm_k<<<gemm_grid, 256, 0, stream>>>(bufB, Wt2, A1, B1, cout_, bufA);
  gather_k<<<gather_grid, 256, 0, stream>>>(bufA, csr_src, csr_w, offs, cin, bufB, sx2, sq2);
  stats_k<<<stats_grid, HID, 0, stream>>>(sx2, sq2, g2a, g2g, g2b, A2, B2);
  phi_pool_k<<<gemm_grid, 256, 0, stream>>>(bufB, A2, B2, Rt2, r2b1, ps2, hs2);
  finalize_k<<<NG, 64, 0, stream>>>(ps2, hs2, r2w2, r2b2, out, 192, 256);
}

// Round 6
// 374.377 us; speedup vs baseline: 19.5673x; 1.4845x over previous
//
#include <hip/hip_runtime.h>
#include <cstddef>
#include <cstdint>

#define NG   100
#define NPG  1000
#define NN   (NG * NPG)       // 100000 nodes
#define NE   (NN * 16)        // 1600000 edges
#define EPG  (NE / NG)        // 16000 edges per graph (edges are graph-local)
#define FIN  64
#define HID  128
#define RD   64
#define SLOPE 0.01f
#define EPSV  1e-5f
#define NSTRIP 250            // nodes per GEMM/phi block (4 strips per graph)
#define GSN   40              // nodes per gather block (25 strips per graph)

using short8 = __attribute__((ext_vector_type(8))) short;   // 8 bf16 = 4 VGPRs
using f32x4  = __attribute__((ext_vector_type(4))) float;
typedef unsigned short u16;

__device__ __forceinline__ float leaky(float x) { return x >= 0.f ? x : SLOPE * x; }

// fp32 -> bf16 (round-to-nearest-even), bit pattern
__device__ __forceinline__ u16 f2bf(float f) {
  union { float f; unsigned u; } v; v.f = f;
  return (u16)((v.u + 0x7fffu + ((v.u >> 16) & 1u)) >> 16);
}
__device__ __forceinline__ float bf2f(u16 u) {
  union { unsigned u; float f; } v; v.u = ((unsigned)u) << 16;
  return v.f;
}

// XCD-affinity swizzle: block->XCD heuristic is blockIdx%8; pin graph g to
// XCD g%8 so producer/consumer blocks of one graph share an L2.
__device__ __forceinline__ bool swz(int b, int per_g, int& g, int& part) {
  const int xcd = b & 7;
  const int slot = b >> 3;
  g = xcd + 8 * (slot / per_g);
  part = slot % per_g;
  return g < NG;
}

// ---------------------------------------------------------------------------
// One-shot bf16 transpose of the four GEMM weight matrices: Wt[n][k]=W[k][n].
// ---------------------------------------------------------------------------
__global__ __launch_bounds__(256) void wt_k(const float* __restrict__ W1,
                                            const float* __restrict__ W2,
                                            const float* __restrict__ R1,
                                            const float* __restrict__ R2,
                                            u16* __restrict__ Wt1,
                                            u16* __restrict__ Wt2,
                                            u16* __restrict__ Rt1,
                                            u16* __restrict__ Rt2) {
  const int idx = blockIdx.x * 256 + threadIdx.x;  // 57344 total
  if (idx < FIN * HID) {
    const int n = idx >> 6, k = idx & 63;          // Wt1 [128][64]
    Wt1[idx] = f2bf(W1[k * HID + n]);
  } else {
    const int j = idx - FIN * HID;
    const int m = j >> 14, r = j & 16383;
    const int n = r >> 7, k = r & 127;
    const float* s = (m == 0) ? W2 : (m == 1) ? R1 : R2;
    u16* d = (m == 0) ? Wt2 : (m == 1) ? Rt1 : Rt2;
    d[r] = f2bf(s[k * HID + n]);
  }
}

// ---------------------------------------------------------------------------
// Per-graph CSR build, fully in one kernel (LDS histograms + scan + cursors):
//   pass1: in/out degree histograms over the graph's 16000 edges,
//   write cin/cout, exclusive-scan hin -> offs + LDS cursor,
//   pass2: slot each edge's (src,w) under its dst bucket.
// One 1024-thread block per graph; no global atomics, no memset needed.
// ---------------------------------------------------------------------------
__global__ __launch_bounds__(1024) void build_k(const int* __restrict__ src,
                                                const int* __restrict__ dst,
                                                const float* __restrict__ ew,
                                                int* __restrict__ cin_,
                                                int* __restrict__ cout_,
                                                int* __restrict__ offs,
                                                int* __restrict__ csr_src,
                                                float* __restrict__ csr_w) {
  __shared__ int hin[NPG];
  __shared__ int hout[NPG];
  __shared__ int tsum[1024];
  __shared__ int cur[NPG];
  const int g = blockIdx.x;
  const int t = threadIdx.x;
  const int nb = g * NPG;     // node base
  const int eb = g * EPG;     // edge base
  if (t < NPG) { hin[t] = 0; hout[t] = 0; }
  __syncthreads();
  for (int e = t; e < EPG; e += 1024) {
    atomicAdd(&hout[src[eb + e] - nb], 1);
    atomicAdd(&hin[dst[eb + e] - nb], 1);
  }
  __syncthreads();
  int myc = 0;
  if (t < NPG) {
    myc = hin[t];
    cin_[nb + t] = myc;
    cout_[nb + t] = hout[t];
  }
  tsum[t] = myc;
  __syncthreads();
  for (int d = 1; d < 1024; d <<= 1) {
    int x = (t >= d) ? tsum[t - d] : 0;
    __syncthreads();
    tsum[t] += x;
    __syncthreads();
  }
  if (t < NPG) {
    const int run = (t > 0 ? tsum[t - 1] : 0) + eb;
    offs[nb + t] = run;
    cur[t] = run;
  }
  __syncthreads();
  for (int e = t; e < EPG; e += 1024) {
    const int d = dst[eb + e] - nb;
    const int pos = atomicAdd(&cur[d], 1);
    csr_src[pos] = src[eb + e];
    csr_w[pos] = ew[eb + e];
  }
}

// ---------------------------------------------------------------------------
// Layer-1 GEMM (MFMA bf16), XCD-swizzled, 250-row strips, bf16 output.
// LDS: unpadded rows, 8-bf16 chunks XOR-swizzled by (row & mask).
// A-frag A[m=lane&15][k=quad*8+j]; B-frag B[k=quad*8+j][n=lane&15];
// C/D col=lane&15, row=quad*4+reg (m89-verified).
// ---------------------------------------------------------------------------
__global__ __launch_bounds__(256) void gemm1_k(const float* __restrict__ X,
                                               const u16* __restrict__ Wt,
                                               const int* __restrict__ cout_,
                                               u16* __restrict__ Y) {
  __shared__ u16 Xl[64 * FIN];
  __shared__ u16 Wl[HID * FIN];
  const int tid = threadIdx.x;
  const int wave = tid >> 6, lane = tid & 63, l15 = lane & 15, quad = lane >> 4;
  int g, part;
  if (!swz(blockIdx.x, 4, g, part)) return;
  const int base = g * NPG + part * NSTRIP;

  for (int i = tid; i < HID * (FIN / 8); i += 256) {  // 1024 chunks
    const int n = i >> 3, c = i & 7;
    const short8 w = *(const short8*)(Wt + n * FIN + c * 8);
    *(short8*)&Wl[n * FIN + ((c ^ (n & 7)) << 3)] = w;
  }
  for (int pass = 0; pass < 4; ++pass) {
    __syncthreads();
    for (int i = tid; i < 64 * (FIN / 4); i += 256) {  // 1024
      const int r = i >> 4;
      const int kq = i & 15;
      const int rowi = pass * 64 + r;
      ushort4 u = make_ushort4(0, 0, 0, 0);
      if (rowi < NSTRIP) {
        const float4 x = *(const float4*)(X + (size_t)(base + rowi) * FIN + kq * 4);
        u.x = f2bf(x.x); u.y = f2bf(x.y); u.z = f2bf(x.z); u.w = f2bf(x.w);
      }
      const int c = kq >> 1, half = kq & 1;
      *(ushort4*)&Xl[r * FIN + (((c ^ (r & 7)) << 3) | (half << 2))] = u;
    }
    __syncthreads();
    short8 a[2];
    const int arow = wave * 16 + l15;
#pragma unroll
    for (int kt = 0; kt < 2; ++kt)
      a[kt] = *(const short8*)&Xl[arow * FIN + (((kt * 4 + quad) ^ (l15 & 7)) << 3)];
    float sc[4];
    int rows[4];
#pragma unroll
    for (int r = 0; r < 4; ++r) {
      rows[r] = pass * 64 + wave * 16 + quad * 4 + r;
      sc[r] = (rows[r] < NSTRIP) ? rsqrtf(fmaxf((float)cout_[base + rows[r]], 1.0f)) : 0.f;
    }
#pragma unroll
    for (int ct = 0; ct < 8; ++ct) {
      f32x4 acc = {0.f, 0.f, 0.f, 0.f};
      const int brow = ct * 16 + l15;
#pragma unroll
      for (int kt = 0; kt < 2; ++kt) {
        const short8 b = *(const short8*)&Wl[brow * FIN + (((kt * 4 + quad) ^ (l15 & 7)) << 3)];
        acc = __builtin_amdgcn_mfma_f32_16x16x32_bf16(a[kt], b, acc, 0, 0, 0);
      }
      const int n = ct * 16 + l15;
#pragma unroll
      for (int r = 0; r < 4; ++r)
        if (rows[r] < NSTRIP) Y[(size_t)(base + rows[r]) * HID + n] = f2bf(acc[r] * sc[r]);
    }
  }
}

// ---------------------------------------------------------------------------
// Layer-2 GEMM (MFMA bf16), fused GraphNorm apply, bf16 in/out, XCD-swizzled.
// ---------------------------------------------------------------------------
__global__ __launch_bounds__(256) void gemm_norm_k(const u16* __restrict__ Xb,
                                                   const u16* __restrict__ Wt,
                                                   const float* __restrict__ An,
                                                   const float* __restrict__ Bn,
                                                   const int* __restrict__ cout_,
                                                   u16* __restrict__ Y) {
  __shared__ u16 Xl[64 * HID];
  __shared__ u16 Wl[HID * HID];
  const int tid = threadIdx.x;
  const int wave = tid >> 6, lane = tid & 63, l15 = lane & 15, quad = lane >> 4;
  int g, part;
  if (!swz(blockIdx.x, 4, g, part)) return;
  const int base = g * NPG + part * NSTRIP;

  for (int i = tid; i < HID * (HID / 8); i += 256) {  // 2048 chunks
    const int n = i >> 4, c = i & 15;
    const short8 w = *(const short8*)(Wt + n * HID + c * 8);
    *(short8*)&Wl[n * HID + ((c ^ (n & 15)) << 3)] = w;
  }
  for (int pass = 0; pass < 4; ++pass) {
    __syncthreads();
    for (int i = tid; i < 64 * 16; i += 256) {  // 4 iters, 8 elems each
      const int r = i >> 4;
      const int c8 = i & 15;
      const int rowi = pass * 64 + r;
      short8 o = {0, 0, 0, 0, 0, 0, 0, 0};
      if (rowi < NSTRIP) {
        const int node = base + rowi;
        const short8 xs = *(const short8*)(Xb + (size_t)node * HID + c8 * 8);
        const float4 Aa = *(const float4*)(An + (size_t)g * HID + c8 * 8);
        const float4 Ab = *(const float4*)(An + (size_t)g * HID + c8 * 8 + 4);
        const float4 Ba = *(const float4*)(Bn + (size_t)g * HID + c8 * 8);
        const float4 Bb = *(const float4*)(Bn + (size_t)g * HID + c8 * 8 + 4);
        const float Av[8] = {Aa.x, Aa.y, Aa.z, Aa.w, Ab.x, Ab.y, Ab.z, Ab.w};
        const float Bv[8] = {Ba.x, Ba.y, Ba.z, Ba.w, Bb.x, Bb.y, Bb.z, Bb.w};
#pragma unroll
        for (int j = 0; j < 8; ++j)
          o[j] = (short)f2bf(leaky(fmaf(Av[j], bf2f((u16)xs[j]), Bv[j])));
      }
      *(short8*)&Xl[r * HID + ((c8 ^ (r & 15)) << 3)] = o;
    }
    __syncthreads();
    short8 a[4];
    const int arow = wave * 16 + l15;
#pragma unroll
    for (int kt = 0; kt < 4; ++kt)
      a[kt] = *(const short8*)&Xl[arow * HID + (((kt * 4 + quad) ^ l15) << 3)];
    float sc[4];
    int rows[4];
#pragma unroll
    for (int r = 0; r < 4; ++r) {
      rows[r] = pass * 64 + wave * 16 + quad * 4 + r;
      sc[r] = (rows[r] < NSTRIP) ? rsqrtf(fmaxf((float)cout_[base + rows[r]], 1.0f)) : 0.f;
    }
#pragma unroll
    for (int ct = 0; ct < 8; ++ct) {
      f32x4 acc = {0.f, 0.f, 0.f, 0.f};
      const int brow = ct * 16 + l15;
#pragma unroll
      for (int kt = 0; kt < 4; ++kt) {
        const short8 b = *(const short8*)&Wl[brow * HID + (((kt * 4 + quad) ^ l15) << 3)];
        acc = __builtin_amdgcn_mfma_f32_16x16x32_bf16(a[kt], b, acc, 0, 0, 0);
      }
      const int n = ct * 16 + l15;
#pragma unroll
      for (int r = 0; r < 4; ++r)
        if (rows[r] < NSTRIP) Y[(size_t)(base + rows[r]) * HID + n] = f2bf(acc[r] * sc[r]);
    }
  }
}

// ---------------------------------------------------------------------------
// Readout phi+pool (MFMA bf16), fused norm apply, bf16 input, XCD-swizzled.
// ---------------------------------------------------------------------------
__global__ __launch_bounds__(256) void phi_pool_k(const u16* __restrict__ Xb,
                                                  const float* __restrict__ An,
                                                  const float* __restrict__ Bn,
                                                  const u16* __restrict__ Wt,
                                                  const float* __restrict__ b1,
                                                  float* __restrict__ phi_sum,
                                                  float* __restrict__ h_sum) {
  __shared__ u16 Xl[64 * HID];          // 16 KB
  __shared__ u16 Wl[HID * HID];         // 32 KB
  __shared__ float red[16][HID];        //  8 KB
  __shared__ float hred[16][HID];       //  8 KB  (64 KB total)
  const int tid = threadIdx.x;
  const int wave = tid >> 6, lane = tid & 63, l15 = lane & 15, quad = lane >> 4;
  int g, part;
  if (!swz(blockIdx.x, 4, g, part)) return;
  const int base = g * NPG + part * NSTRIP;

  for (int i = tid; i < HID * (HID / 8); i += 256) {
    const int n = i >> 4, c = i & 15;
    const short8 w = *(const short8*)(Wt + n * HID + c * 8);
    *(short8*)&Wl[n * HID + ((c ^ (n & 15)) << 3)] = w;
  }
  float bcol[8];
#pragma unroll
  for (int ct = 0; ct < 8; ++ct) bcol[ct] = b1[ct * 16 + l15];

  float pooled[8] = {0.f, 0.f, 0.f, 0.f, 0.f, 0.f, 0.f, 0.f};
  float hp[8] = {0.f, 0.f, 0.f, 0.f, 0.f, 0.f, 0.f, 0.f};

  for (int pass = 0; pass < 4; ++pass) {
    __syncthreads();
    for (int i = tid; i < 64 * 16; i += 256) {
      const int r = i >> 4;
      const int c8 = i & 15;   // == tid&15 (stride 256)
      const int rowi = pass * 64 + r;
      short8 o = {0, 0, 0, 0, 0, 0, 0, 0};
      if (rowi < NSTRIP) {
        const int node = base + rowi;
        const short8 xs = *(const short8*)(Xb + (size_t)node * HID + c8 * 8);
        const float4 Aa = *(const float4*)(An + (size_t)g * HID + c8 * 8);
        const float4 Ab = *(const float4*)(An + (size_t)g * HID + c8 * 8 + 4);
        const float4 Ba = *(const float4*)(Bn + (size_t)g * HID + c8 * 8);
        const float4 Bb = *(const float4*)(Bn + (size_t)g * HID + c8 * 8 + 4);
        const float Av[8] = {Aa.x, Aa.y, Aa.z, Aa.w, Ab.x, Ab.y, Ab.z, Ab.w};
        const float Bv[8] = {Ba.x, Ba.y, Ba.z, Ba.w, Bb.x, Bb.y, Bb.z, Bb.w};
#pragma unroll
        for (int j = 0; j < 8; ++j) {
          const float xn = leaky(fmaf(Av[j], bf2f((u16)xs[j]), Bv[j]));
          hp[j] += xn;
          o[j] = (short)f2bf(xn);
        }
      }
      *(short8*)&Xl[r * HID + ((c8 ^ (r & 15)) << 3)] = o;
    }
    __syncthreads();
    short8 a[4];
    const int arow = wave * 16 + l15;
#pragma unroll
    for (int kt = 0; kt < 4; ++kt)
      a[kt] = *(const short8*)&Xl[arow * HID + (((kt * 4 + quad) ^ l15) << 3)];
#pragma unroll
    for (int ct = 0; ct < 8; ++ct) {
      f32x4 acc = {0.f, 0.f, 0.f, 0.f};
      const int brow = ct * 16 + l15;
#pragma unroll
      for (int kt = 0; kt < 4; ++kt) {
        const short8 b = *(const short8*)&Wl[brow * HID + (((kt * 4 + quad) ^ l15) << 3)];
        acc = __builtin_amdgcn_mfma_f32_16x16x32_bf16(a[kt], b, acc, 0, 0, 0);
      }
#pragma unroll
      for (int r = 0; r < 4; ++r) {
        const int rowi = pass * 64 + wave * 16 + quad * 4 + r;
        if (rowi < NSTRIP) pooled[ct] += leaky(acc[r] + bcol[ct]);
      }
    }
  }
  const int qi = wave * 4 + quad;
#pragma unroll
  for (int ct = 0; ct < 8; ++ct) red[qi][ct * 16 + l15] = pooled[ct];
#pragma unroll
  for (int j = 0; j < 8; ++j) hred[tid >> 4][(tid & 15) * 8 + j] = hp[j];
  __syncthreads();
  if (tid < HID) {
    float s = 0.f;
#pragma unroll
    for (int q = 0; q < 16; ++q) s += red[q][tid];
    unsafeAtomicAdd(&phi_sum[g * HID + tid], s);
  } else {
    const int t = tid - HID;
    float s = 0.f;
#pragma unroll
    for (int rr = 0; rr < 16; ++rr) s += hred[rr][t];
    unsafeAtomicAdd(&h_sum[g * HID + t], s);
  }
}

// ---------------------------------------------------------------------------
// Atomic-free aggregation (bf16 in/out) + in_isqrt + fused per-graph stats.
// 4 edges in flight; one dword (2 bf16 feats) per lane per edge.
// ---------------------------------------------------------------------------
__global__ __launch_bounds__(256) void gather_k(const u16* __restrict__ H,
                                                const int* __restrict__ csr_src,
                                                const float* __restrict__ csr_w,
                                                const int* __restrict__ offs,
                                                const int* __restrict__ cin_,
                                                u16* __restrict__ AGG,
                                                float* __restrict__ sx,
                                                float* __restrict__ sq) {
  __shared__ float redx[4][HID];
  __shared__ float redq[4][HID];
  const int wave = threadIdx.x >> 6;
  const int lane = threadIdx.x & 63;
  int g, part;
  if (!swz(blockIdx.x, 25, g, part)) return;
  const int base = g * NPG + part * GSN;

  float sxa = 0.f, sxb = 0.f, sqa = 0.f, sqb = 0.f;
  for (int n = base + wave; n < base + GSN; n += 4) {
    const int off = offs[n];
    const int cnt = cin_[n];
    const float isq = rsqrtf(fmaxf((float)cnt, 1.0f));
    float ax = 0.f, ay = 0.f, bx = 0.f, by = 0.f;
    int i = 0;
    while (i < cnt) {
      const int take = min(cnt - i, 64);
      int sv = 0; float wv = 0.f;
      if (lane < take) {
        sv = csr_src[off + i + lane];
        wv = csr_w[off + i + lane];
      }
      int t = 0;
      for (; t + 4 <= take; t += 4) {
        const int s0 = __shfl(sv, t), s1 = __shfl(sv, t + 1);
        const int s2 = __shfl(sv, t + 2), s3 = __shfl(sv, t + 3);
        const float w0 = __shfl(wv, t), w1 = __shfl(wv, t + 1);
        const float w2 = __shfl(wv, t + 2), w3 = __shfl(wv, t + 3);
        const unsigned u0 = *(const unsigned*)(H + (size_t)s0 * HID + lane * 2);
        const unsigned u1 = *(const unsigned*)(H + (size_t)s1 * HID + lane * 2);
        const unsigned u2 = *(const unsigned*)(H + (size_t)s2 * HID + lane * 2);
        const unsigned u3 = *(const unsigned*)(H + (size_t)s3 * HID + lane * 2);
        ax = fmaf(w0, __uint_as_float(u0 << 16), ax);
        ay = fmaf(w0, __uint_as_float(u0 & 0xffff0000u), ay);
        bx = fmaf(w1, __uint_as_float(u1 << 16), bx);
        by = fmaf(w1, __uint_as_float(u1 & 0xffff0000u), by);
        ax = fmaf(w2, __uint_as_float(u2 << 16), ax);
        ay = fmaf(w2, __uint_as_float(u2 & 0xffff0000u), ay);
        bx = fmaf(w3, __uint_as_float(u3 << 16), bx);
        by = fmaf(w3, __uint_as_float(u3 & 0xffff0000u), by);
      }
      for (; t < take; ++t) {
        const int s0 = __shfl(sv, t);
        const float w0 = __shfl(wv, t);
        const unsigned u0 = *(const unsigned*)(H + (size_t)s0 * HID + lane * 2);
        ax = fmaf(w0, __uint_as_float(u0 << 16), ax);
        ay = fmaf(w0, __uint_as_float(u0 & 0xffff0000u), ay);
      }
      i += take;
    }
    const float rx = (ax + bx) * isq;
    const float ry = (ay + by) * isq;
    const unsigned pk = (unsigned)f2bf(rx) | ((unsigned)f2bf(ry) << 16);
    *(unsigned*)(AGG + (size_t)n * HID + lane * 2) = pk;
    sxa += rx; sxb += ry;
    sqa += rx * rx; sqb += ry * ry;
  }
  redx[wave][lane * 2] = sxa; redx[wave][lane * 2 + 1] = sxb;
  redq[wave][lane * 2] = sqa; redq[wave][lane * 2 + 1] = sqb;
  __syncthreads();
  const int tid = threadIdx.x;
  if (tid < HID) {
    unsafeAtomicAdd(&sx[g * HID + tid],
                    redx[0][tid] + redx[1][tid] + redx[2][tid] + redx[3][tid]);
  } else {
    const int t = tid - HID;
    unsafeAtomicAdd(&sq[g * HID + t],
                    redq[0][t] + redq[1][t] + redq[2][t] + redq[3][t]);
  }
}

// ---------------------------------------------------------------------------
// Fold stats into affine: normalized = A*x + B per (graph, feat).
// ---------------------------------------------------------------------------
__global__ __launch_bounds__(HID) void stats_k(const float* __restrict__ sx,
                                               const float* __restrict__ sq,
                                               const float* __restrict__ alpha,
                                               const float* __restrict__ gamma,
                                               const float* __restrict__ beta,
                                               float* __restrict__ An,
                                               float* __restrict__ Bn) {
  const int g = (blockIdx.x & 7) + 8 * (blockIdx.x >> 3);
  if (g >= NG) return;
  const int j = threadIdx.x;
  const float mean = sx[g * HID + j] * (1.0f / NPG);
  const float ex2 = sq[g * HID + j] * (1.0f / NPG);
  const float am = alpha[j] * mean;
  float var = ex2 - 2.0f * am * mean + am * am;
  var = fmaxf(var, 0.0f);
  const float rstd = rsqrtf(var + EPSV);
  const float A = gamma[j] * rstd;
  An[g * HID + j] = A;
  Bn[g * HID + j] = beta[j] - A * am;
}

// ---------------------------------------------------------------------------
// Readout part 2.
// ---------------------------------------------------------------------------
__global__ __launch_bounds__(64) void finalize_k(const float* __restrict__ phi_sum,
                                                 const float* __restrict__ h_sum,
                                                 const float* __restrict__ w2,
                                                 const float* __restrict__ b2,
                                                 float* __restrict__ out,
                                                 int roff, int moff) {
  const int g = blockIdx.x;
  const int j = threadIdx.x;  // 0..63
  float acc = b2[j];
#pragma unroll 8
  for (int k = 0; k < HID; ++k)
    acc += (phi_sum[g * HID + k] * (1.0f / NPG)) * w2[k * RD + j];
  const float r = leaky(acc);
  out[g * 384 + roff + j] = leaky(r);
  out[g * 384 + moff + j] = leaky(h_sum[g * HID + j] * (1.0f / NPG));
  out[g * 384 + moff + 64 + j] = leaky(h_sum[g * HID + 64 + j] * (1.0f / NPG));
}

// ---------------------------------------------------------------------------
extern "C" void kernel_launch(void* const* d_in, const int* in_sizes, int n_in,
                              void* d_out, int out_size, void* d_ws, size_t ws_size,
                              hipStream_t stream) {
  const float* node_feats = (const float*)d_in[0];
  const float* ew   = (const float*)d_in[1];
  const float* W1   = (const float*)d_in[2];
  const float* W2   = (const float*)d_in[3];
  const float* g1a  = (const float*)d_in[4];
  const float* g1g  = (const float*)d_in[5];
  const float* g1b  = (const float*)d_in[6];
  const float* g2a  = (const float*)d_in[7];
  const float* g2g  = (const float*)d_in[8];
  const float* g2b  = (const float*)d_in[9];
  const float* r1w1 = (const float*)d_in[10];
  const float* r1b1 = (const float*)d_in[11];
  const float* r1w2 = (const float*)d_in[12];
  const float* r1b2 = (const float*)d_in[13];
  const float* r2w1 = (const float*)d_in[14];
  const float* r2b1 = (const float*)d_in[15];
  const float* r2w2 = (const float*)d_in[16];
  const float* r2b2 = (const float*)d_in[17];
  const int* src = (const int*)d_in[18];
  const int* dst = (const int*)d_in[19];
  float* out = (float*)d_out;

  // workspace layout (zeroed pooled-sum region first)
  char* wsb = (char*)d_ws;
  float* ps1     = (float*)wsb;                       // NG*HID x8, zeroed
  float* hs1     = ps1 + NG * HID;
  float* ps2     = hs1 + NG * HID;
  float* hs2     = ps2 + NG * HID;
  float* sx1     = hs2 + NG * HID;
  float* sq1     = sx1 + NG * HID;
  float* sx2     = sq1 + NG * HID;
  float* sq2     = sx2 + NG * HID;
  int*   cin     = (int*)(sq2 + NG * HID);            // NN
  int*   cout_   = cin + NN;                          // NN
  int*   offs    = cout_ + NN;                        // NN
  int*   csr_src = offs + NN;                         // NE
  float* csr_w   = (float*)(csr_src + NE);            // NE
  float* A1      = csr_w + NE;                        // NG*HID x4
  float* B1      = A1 + NG * HID;
  float* A2      = B1 + NG * HID;
  float* B2      = A2 + NG * HID;
  u16*   Wt1     = (u16*)(B2 + NG * HID);             // 128*64
  u16*   Wt2     = Wt1 + HID * FIN;                   // 128*128 x3
  u16*   Rt1     = Wt2 + HID * HID;
  u16*   Rt2     = Rt1 + HID * HID;
  u16*   bufA    = Rt2 + HID * HID;                   // NN*HID bf16
  u16*   bufB    = bufA + (size_t)NN * HID;           // NN*HID bf16

  hipMemsetAsync(d_ws, 0, (size_t)(8 * NG * HID) * sizeof(float), stream);

  // one-shot weight transpose to bf16 + CSR build (re-done each call)
  wt_k<<<(FIN * HID + 3 * HID * HID) / 256, 256, 0, stream>>>(
      W1, W2, r1w1, r2w1, Wt1, Wt2, Rt1, Rt2);
  build_k<<<NG, 1024, 0, stream>>>(src, dst, ew, cin, cout_, offs, csr_src, csr_w);

  const int gemm_grid = 8 * 4 * 13;     // XCD-swizzled, 4 strips/graph
  const int gather_grid = 8 * 25 * 13;  // XCD-swizzled, 25 strips/graph
  const int stats_grid = 8 * 13;

  // ---- layer 1 ----
  gemm1_k<<<gemm_grid, 256, 0, stream>>>(node_feats, Wt1, cout_, bufA);
  gather_k<<<gather_grid, 256, 0, stream>>>(bufA, csr_src, csr_w, offs, cin, bufB, sx1, sq1);
  stats_k<<<stats_grid, HID, 0, stream>>>(sx1, sq1, g1a, g1g, g1b, A1, B1);
  phi_pool_k<<<gemm_grid, 256, 0, stream>>>(bufB, A1, B1, Rt1, r1b1, ps1, hs1);
  finalize_k<<<NG, 64, 0, stream>>>(ps1, hs1, r1w2, r1b2, out, 0, 64);

  // ---- layer 2 ----
  gemm_norm_k<<<gemm_grid, 256, 0, stream>>>(bufB, Wt2, A1, B1, cout_, bufA);
  gather_k<<<gather_grid, 256, 0, stream>>>(bufA, csr_src, csr_w, offs, cin, bufB, sx2, sq2);
  stats_k<<<stats_grid, HID, 0, stream>>>(sx2, sq2, g2a, g2g, g2b, A2, B2);
  phi_pool_k<<<gemm_grid, 256, 0, stream>>>(bufB, A2, B2, Rt2, r2b1, ps2, hs2);
  finalize_k<<<NG, 64, 0, stream>>>(ps2, hs2, r2w2, r2b2, out, 192, 256);
}